// Round 7
// baseline (449.645 us; speedup 1.0000x reference)
//
#include <hip/hip_runtime.h>

#define NN 10000
#define NE 256000
#define H 128
#define H2 256
#define H3 384
#define NRBF 20

typedef __attribute__((ext_vector_type(8))) short bf16x8;
typedef __attribute__((ext_vector_type(4))) float f32x4;

__device__ __forceinline__ float silu_f(float v) { return v / (1.f + __expf(-v)); }

// fp32 -> bf16 bits (RNE)
__device__ __forceinline__ unsigned short f2b(float f) {
    union { float f; unsigned u; } x; x.f = f;
    unsigned r = (x.u + 0x7FFFu + ((x.u >> 16) & 1u)) >> 16;
    return (unsigned short)r;
}
__device__ __forceinline__ float b2f(unsigned short b) {
    union { unsigned u; float f; } x; x.u = ((unsigned)b) << 16;
    return x.f;
}

// ---------------------------------------------------------------------------
// CSR build
// ---------------------------------------------------------------------------
__global__ __launch_bounds__(256) void hist_kernel(const int* __restrict__ eidx,
                                                   int* __restrict__ counts) {
    int e = blockIdx.x * 256 + threadIdx.x;
    atomicAdd(&counts[eidx[e]], 1);
}

__global__ __launch_bounds__(1024) void scan_kernel(const int* __restrict__ counts,
                                                    int* __restrict__ off,
                                                    int* __restrict__ cursor) {
    __shared__ int sums[1024];
    const int t = threadIdx.x;
    const int base = t * 10;
    int local[10];
    int s = 0;
    #pragma unroll
    for (int i = 0; i < 10; i++) {
        int idx = base + i;
        int v = (idx < NN) ? counts[idx] : 0;
        local[i] = s; s += v;
    }
    sums[t] = s;
    __syncthreads();
    for (int d = 1; d < 1024; d <<= 1) {
        int v = (t >= d) ? sums[t - d] : 0;
        __syncthreads();
        sums[t] += v;
        __syncthreads();
    }
    int prefix = (t > 0) ? sums[t - 1] : 0;
    #pragma unroll
    for (int i = 0; i < 10; i++) {
        int idx = base + i;
        if (idx < NN) { off[idx] = prefix + local[i]; cursor[idx] = prefix + local[i]; }
    }
    if (t == 1023) off[NN] = sums[1023];
}

__global__ __launch_bounds__(256) void place_kernel(
    const int* __restrict__ eidx, const float* __restrict__ unitv,
    int* __restrict__ cursor, int* __restrict__ sorted_eid,
    int* __restrict__ sorted_src, float* __restrict__ sorted_unit) {
    int e = blockIdx.x * 256 + threadIdx.x;
    int tgt = eidx[e];
    int src = eidx[NE + e];
    int pos = atomicAdd(&cursor[tgt], 1);
    sorted_eid[pos] = e;
    sorted_src[pos] = src;
    sorted_unit[pos * 3 + 0] = unitv[(size_t)e * 3 + 0];
    sorted_unit[pos * 3 + 1] = unitv[(size_t)e * 3 + 1];
    sorted_unit[pos * 3 + 2] = unitv[(size_t)e * 3 + 2];
}

// ---------------------------------------------------------------------------
// Unified weight packing (one launch). 64-thread blocks, range-switched.
// ---------------------------------------------------------------------------
__device__ __forceinline__ void pack_hi_one(const float* __restrict__ W, int K, int N,
                                            unsigned short* __restrict__ dst,
                                            int b, int lane) {
    const int KT = K >> 5;
    const int kt = b % KT, ct = b / KT;
    const int m = lane & 15, qd = lane >> 4;
    size_t base = ((size_t)(ct * KT + kt) * 64 + lane) * 8;
    unsigned short v[8];
    #pragma unroll
    for (int j = 0; j < 8; j++) {
        int k = kt * 32 + qd * 8 + j;
        v[j] = f2b(W[(size_t)k * N + ct * 16 + m]);
    }
    *(ushort4*)&dst[base]     = *(ushort4*)&v[0];
    *(ushort4*)&dst[base + 4] = *(ushort4*)&v[4];
}

__device__ __forceinline__ void pack_split_one(const float* __restrict__ W, int K, int N,
                                               unsigned short* __restrict__ hi,
                                               unsigned short* __restrict__ lo,
                                               int b, int lane) {
    const int KT = K >> 5;
    const int kt = b % KT, ct = b / KT;
    const int m = lane & 15, qd = lane >> 4;
    size_t base = ((size_t)(ct * KT + kt) * 64 + lane) * 8;
    #pragma unroll
    for (int j = 0; j < 8; j++) {
        int k = kt * 32 + qd * 8 + j;
        float v = W[(size_t)k * N + ct * 16 + m];
        unsigned short h = f2b(v);
        hi[base + j] = h;
        lo[base + j] = f2b(v - b2f(h));
    }
}

__global__ __launch_bounds__(64) void pack_all_kernel(
    const float* __restrict__ Wf2, const float* __restrict__ Wi1,
    const float* __restrict__ Wi2, const float* __restrict__ Wf1,
    const float* __restrict__ Wv, const float* __restrict__ Wm1,
    const float* __restrict__ Wm2,
    unsigned short* __restrict__ Bp, unsigned short* __restrict__ Bp1,
    unsigned short* __restrict__ Bp2, unsigned short* __restrict__ Bf1p,
    unsigned short* __restrict__ Bv_hi, unsigned short* __restrict__ Bv_lo,
    unsigned short* __restrict__ B1_hi, unsigned short* __restrict__ B1_lo,
    unsigned short* __restrict__ B2_hi, unsigned short* __restrict__ B2_lo) {
    const int b = blockIdx.x;
    const int lane = threadIdx.x;
    if (b < 96)        pack_hi_one(Wf2, H, H3, Bp, b, lane);
    else if (b < 192)  pack_hi_one(Wi1, H, H3, Bp1, b - 96, lane);
    else if (b < 480)  pack_hi_one(Wi2, H3, H3, Bp2, b - 192, lane);
    else if (b < 488) {                               // Wf1: K=20 zero-padded to 32
        const int ct = b - 480;
        const int m = lane & 15, qd = lane >> 4;
        size_t base = ((size_t)ct * 64 + lane) * 8;
        unsigned short v[8];
        #pragma unroll
        for (int j = 0; j < 8; j++) {
            int k = qd * 8 + j;
            v[j] = (k < NRBF) ? f2b(Wf1[(size_t)k * H + ct * 16 + m]) : (unsigned short)0;
        }
        *(ushort4*)&Bf1p[base]     = *(ushort4*)&v[0];
        *(ushort4*)&Bf1p[base + 4] = *(ushort4*)&v[4];
    }
    else if (b < 552)  pack_split_one(Wv,  H,  H2, Bv_hi, Bv_lo, b - 488, lane);
    else if (b < 744)  pack_split_one(Wm1, H2, H3, B1_hi, B1_lo, b - 552, lane);
    else if (b < 1032) pack_split_one(Wm2, H3, H3, B2_hi, B2_lo, b - 744, lane);
}

// mu fp32 -> bf16 copy
__global__ __launch_bounds__(256) void mu2b_kernel(const float* __restrict__ mu,
                                                   unsigned short* __restrict__ mu_b) {
    int i = blockIdx.x * 256 + threadIdx.x;
    float4 v = ((const float4*)mu)[i];
    ushort4 o;
    o.x = f2b(v.x); o.y = f2b(v.y); o.z = f2b(v.z); o.w = f2b(v.w);
    ((ushort4*)mu_b)[i] = o;
}

// ---------------------------------------------------------------------------
// node_x (MFMA): x_b = bf16(silu(q@W1+b1) @ W2 + b2). 32 nodes per block.
// ---------------------------------------------------------------------------
__global__ __launch_bounds__(256) void node_x_kernel(
    const float* __restrict__ q,
    const unsigned short* __restrict__ Bp1, const float* __restrict__ b1,
    const unsigned short* __restrict__ Bp2, const float* __restrict__ b2,
    unsigned short* __restrict__ x_b) {
    __shared__ __align__(16) unsigned short qa_s[32 * 136];
    __shared__ __align__(16) unsigned short h1_s[32 * 392];
    const int t = threadIdx.x;
    const int wv = t >> 6, lane = t & 63;
    const int m = lane & 15, qd = lane >> 4;
    const int st = wv >> 1, ch = wv & 1;
    const int n0 = blockIdx.x * 32;

    for (int i = t; i < 32 * 32; i += 256) {
        int r = i >> 5, c4 = (i & 31) * 4;
        int node = n0 + r;
        ushort4 o;
        if (node < NN) {
            float4 v = *(const float4*)&q[(size_t)node * H + c4];
            o.x = f2b(v.x); o.y = f2b(v.y); o.z = f2b(v.z); o.w = f2b(v.w);
        } else { o.x = o.y = o.z = o.w = 0; }
        *(ushort4*)&qa_s[r * 136 + c4] = o;
    }
    __syncthreads();

    {
        const unsigned short* arow = &qa_s[(st * 16 + m) * 136 + qd * 8];
        #pragma unroll 1
        for (int jc = 0; jc < 12; jc++) {
            int ct = ch * 12 + jc;
            f32x4 acc = {0.f, 0.f, 0.f, 0.f};
            #pragma unroll
            for (int kt = 0; kt < 4; kt++) {
                bf16x8 af = *(const bf16x8*)(arow + kt * 32);
                bf16x8 bfr = *(const bf16x8*)(Bp1 + ((size_t)(ct * 4 + kt) * 64 + lane) * 8);
                acc = __builtin_amdgcn_mfma_f32_16x16x32_bf16(af, bfr, acc, 0, 0, 0);
            }
            int col = ct * 16 + m;
            float bb = b1[col];
            #pragma unroll
            for (int r = 0; r < 4; r++) {
                int row = st * 16 + qd * 4 + r;
                h1_s[row * 392 + col] = f2b(silu_f(acc[r] + bb));
            }
        }
    }
    __syncthreads();

    {
        const unsigned short* arow = &h1_s[(st * 16 + m) * 392 + qd * 8];
        #pragma unroll 1
        for (int jc = 0; jc < 12; jc++) {
            int ct = ch * 12 + jc;
            f32x4 acc = {0.f, 0.f, 0.f, 0.f};
            #pragma unroll
            for (int kt = 0; kt < 12; kt++) {
                bf16x8 af = *(const bf16x8*)(arow + kt * 32);
                bf16x8 bfr = *(const bf16x8*)(Bp2 + ((size_t)(ct * 12 + kt) * 64 + lane) * 8);
                acc = __builtin_amdgcn_mfma_f32_16x16x32_bf16(af, bfr, acc, 0, 0, 0);
            }
            int col = ct * 16 + m;
            float bb = b2[col];
            #pragma unroll
            for (int r = 0; r < 4; r++) {
                int row = n0 + st * 16 + qd * 4 + r;
                if (row < NN) x_b[(size_t)row * H3 + col] = f2b(acc[r] + bb);
            }
        }
    }
}

// ---------------------------------------------------------------------------
// Filter MLP v8: v7 + halved output staging for occupancy.
// R5 counters: occupancy 28% with LDS 50.7KB (3 blocks/CU cap) was the
// binding limit — no pipe saturated. Layer 2 now runs in two column-halves
// with waves REDISTRIBUTED so each half covers contiguous filt cols
// [h*192, h*192+192): wave wv owns col-tiles h*12 + wv*3 + {0,1,2}.
// Each half stages into a 64x200 u16 tile (25.6KB, unioned with
// rbf_s/h1_s) and streams out 384B/row (6 full 64B sectors, h*384
// sector-aligned -> no partial-sector amplification). Weight loads, hfr
// loads, MFMA count unchanged; +2 barriers. LDS 50.7 -> ~26KB; occupancy
// cap 37.5% -> 50% (VGPR=72 -> 16 waves/CU).
// ---------------------------------------------------------------------------
__global__ __launch_bounds__(256) void filter_kernel(
    const float* __restrict__ rbf, const float* __restrict__ cutoff,
    const unsigned short* __restrict__ Bf1p, const float* __restrict__ bf1,
    const unsigned short* __restrict__ Bp, const float* __restrict__ bf2,
    unsigned short* __restrict__ filt) {
    __shared__ __align__(16) char raw_s[64 * 200 * 2];   // 25600 B union
    __shared__ float cut_s[64];
    float (*rbf_s)[21] = (float (*)[21])raw_s;                             // [0, 5376)
    unsigned short (*h1_s)[136] = (unsigned short (*)[136])(raw_s + 5376); // [5376, 22784)
    unsigned short (*out_s)[200] = (unsigned short (*)[200])raw_s;         // [0, 25600)

    const int t = threadIdx.x;
    const int wv = t >> 6, lane = t & 63;
    const int m = lane & 15, qd = lane >> 4;
    const size_t e0 = (size_t)blockIdx.x * 64;

    if (t < 64) cut_s[t] = cutoff[e0 + t];
    for (int i = t; i < 64 * NRBF; i += 256) {          // coalesced
        rbf_s[i / NRBF][i % NRBF] = rbf[e0 * NRBF + i];
    }
    __syncthreads();

    // layer 1 MFMA: wave wv owns slot-tile wv (rows wv*16..wv*16+15)
    {
        bf16x8 af;
        #pragma unroll
        for (int j = 0; j < 8; j++) {
            int k = qd * 8 + j;
            af[j] = (short)((k < NRBF) ? f2b(rbf_s[wv * 16 + m][k]) : (unsigned short)0);
        }
        #pragma unroll
        for (int ct = 0; ct < 8; ct++) {
            f32x4 acc = {0.f, 0.f, 0.f, 0.f};
            bf16x8 bfr = *(const bf16x8*)(Bf1p + ((size_t)ct * 64 + lane) * 8);
            acc = __builtin_amdgcn_mfma_f32_16x16x32_bf16(af, bfr, acc, 0, 0, 0);
            int col = ct * 16 + m;
            float bb = bf1[col];
            #pragma unroll
            for (int r = 0; r < 4; r++) {
                h1_s[wv * 16 + qd * 4 + r][col] = f2b(silu_f(acc[r] + bb));
            }
        }
    }
    __syncthreads();

    // load hfr fragments (all K) + cutoffs to registers; then h1_s is dead
    bf16x8 hfr[4][4];
    #pragma unroll
    for (int et = 0; et < 4; et++) {
        #pragma unroll
        for (int kt = 0; kt < 4; kt++) {
            hfr[et][kt] = *(const bf16x8*)&h1_s[et * 16 + m][qd * 8 + kt * 32];
        }
    }
    float cutv[4];
    #pragma unroll
    for (int et = 0; et < 4; et++) cutv[et] = cut_s[et * 16 + m];
    __syncthreads();   // raw_s becomes out_s

    // layer 2 in two column-halves; each half covers filt cols [h*192, h*192+192)
    #pragma unroll 1
    for (int h = 0; h < 2; h++) {
        #pragma unroll
        for (int cc = 0; cc < 3; cc++) {
            const int ct = h * 12 + wv * 3 + cc;
            bf16x8 w0 = *(const bf16x8*)(Bp + ((size_t)(ct * 4 + 0) * 64 + lane) * 8);
            bf16x8 w1 = *(const bf16x8*)(Bp + ((size_t)(ct * 4 + 1) * 64 + lane) * 8);
            bf16x8 w2 = *(const bf16x8*)(Bp + ((size_t)(ct * 4 + 2) * 64 + lane) * 8);
            bf16x8 w3 = *(const bf16x8*)(Bp + ((size_t)(ct * 4 + 3) * 64 + lane) * 8);
            f32x4 acc0 = {0.f, 0.f, 0.f, 0.f};
            f32x4 acc1 = {0.f, 0.f, 0.f, 0.f};
            f32x4 acc2 = {0.f, 0.f, 0.f, 0.f};
            f32x4 acc3 = {0.f, 0.f, 0.f, 0.f};
            acc0 = __builtin_amdgcn_mfma_f32_16x16x32_bf16(w0, hfr[0][0], acc0, 0, 0, 0);
            acc1 = __builtin_amdgcn_mfma_f32_16x16x32_bf16(w0, hfr[1][0], acc1, 0, 0, 0);
            acc2 = __builtin_amdgcn_mfma_f32_16x16x32_bf16(w0, hfr[2][0], acc2, 0, 0, 0);
            acc3 = __builtin_amdgcn_mfma_f32_16x16x32_bf16(w0, hfr[3][0], acc3, 0, 0, 0);
            acc0 = __builtin_amdgcn_mfma_f32_16x16x32_bf16(w1, hfr[0][1], acc0, 0, 0, 0);
            acc1 = __builtin_amdgcn_mfma_f32_16x16x32_bf16(w1, hfr[1][1], acc1, 0, 0, 0);
            acc2 = __builtin_amdgcn_mfma_f32_16x16x32_bf16(w1, hfr[2][1], acc2, 0, 0, 0);
            acc3 = __builtin_amdgcn_mfma_f32_16x16x32_bf16(w1, hfr[3][1], acc3, 0, 0, 0);
            acc0 = __builtin_amdgcn_mfma_f32_16x16x32_bf16(w2, hfr[0][2], acc0, 0, 0, 0);
            acc1 = __builtin_amdgcn_mfma_f32_16x16x32_bf16(w2, hfr[1][2], acc1, 0, 0, 0);
            acc2 = __builtin_amdgcn_mfma_f32_16x16x32_bf16(w2, hfr[2][2], acc2, 0, 0, 0);
            acc3 = __builtin_amdgcn_mfma_f32_16x16x32_bf16(w2, hfr[3][2], acc3, 0, 0, 0);
            acc0 = __builtin_amdgcn_mfma_f32_16x16x32_bf16(w3, hfr[0][3], acc0, 0, 0, 0);
            acc1 = __builtin_amdgcn_mfma_f32_16x16x32_bf16(w3, hfr[1][3], acc1, 0, 0, 0);
            acc2 = __builtin_amdgcn_mfma_f32_16x16x32_bf16(w3, hfr[2][3], acc2, 0, 0, 0);
            acc3 = __builtin_amdgcn_mfma_f32_16x16x32_bf16(w3, hfr[3][3], acc3, 0, 0, 0);

            float4 bb = *(const float4*)&bf2[ct * 16 + qd * 4];
            const int colL = (wv * 3 + cc) * 16 + qd * 4;     // local col in [0,192)
            #pragma unroll
            for (int et = 0; et < 4; et++) {
                f32x4 a = (et == 0) ? acc0 : (et == 1) ? acc1 : (et == 2) ? acc2 : acc3;
                float c = cutv[et];
                float o0 = (a[0] + bb.x) * c;
                float o1 = (a[1] + bb.y) * c;
                float o2 = (a[2] + bb.z) * c;
                float o3 = (a[3] + bb.w) * c;
                unsigned d0, d1;
                asm("v_cvt_pk_bf16_f32 %0, %1, %2" : "=v"(d0) : "v"(o0), "v"(o1));
                asm("v_cvt_pk_bf16_f32 %0, %1, %2" : "=v"(d1) : "v"(o2), "v"(o3));
                uint2 st; st.x = d0; st.y = d1;
                *(uint2*)&out_s[et * 16 + m][colL] = st;
            }
        }
        __syncthreads();
        // writeout half: 64 rows x 384B contiguous (sector-aligned at h*384)
        #pragma unroll
        for (int i = 0; i < 6; i++) {
            int u = i * 256 + t;
            int row = u / 24, c = u % 24;
            *(uint4*)&filt[(e0 + row) * H3 + h * 192 + c * 8] =
                *(const uint4*)&out_s[row][c * 8];
        }
        __syncthreads();
    }
}

// ---------------------------------------------------------------------------
// Gather: filt indexed through sorted_eid (filter runs in original order).
// ---------------------------------------------------------------------------
__global__ __launch_bounds__(256) void gather_kernel(
    const int* __restrict__ off, const int* __restrict__ sorted_eid,
    const int* __restrict__ sorted_src, const float* __restrict__ sorted_unit,
    const unsigned short* __restrict__ filt,
    const unsigned short* __restrict__ x_b, const unsigned short* __restrict__ mu_b,
    float* __restrict__ acc_q, float* __restrict__ acc_mu) {
    __shared__ float red_s[16][128];
    const int t = threadIdx.x;
    const int n = blockIdx.x;
    const int g = t >> 6, lane = t & 63;
    const int c2 = lane * 2;
    const int j0 = off[n], j1 = off[n + 1];

    float aq0 = 0.f, aq1 = 0.f, a00 = 0.f, a01 = 0.f;
    float a10 = 0.f, a11 = 0.f, a20 = 0.f, a21 = 0.f;
    for (int j = j0 + g; j < j1; j += 4) {
        int e = sorted_eid[j];
        int src = sorted_src[j];
        float u0 = sorted_unit[j * 3 + 0];
        float u1 = sorted_unit[j * 3 + 1];
        float u2 = sorted_unit[j * 3 + 2];
        const unsigned short* frow = filt + (size_t)e * H3 + c2;
        const unsigned short* xrow = x_b + (size_t)src * H3 + c2;
        const unsigned short* murow = mu_b + (size_t)src * H3 + c2;
        ushort2 fq = *(const ushort2*)(frow);
        ushort2 fr = *(const ushort2*)(frow + H);
        ushort2 fm = *(const ushort2*)(frow + 2 * H);
        ushort2 xq = *(const ushort2*)(xrow);
        ushort2 xr = *(const ushort2*)(xrow + H);
        ushort2 xm = *(const ushort2*)(xrow + 2 * H);
        ushort2 m0 = *(const ushort2*)(murow);
        ushort2 m1 = *(const ushort2*)(murow + H);
        ushort2 m2 = *(const ushort2*)(murow + 2 * H);
        float xrs0 = b2f(xr.x) * b2f(fr.x), xrs1 = b2f(xr.y) * b2f(fr.y);
        float xms0 = b2f(xm.x) * b2f(fm.x), xms1 = b2f(xm.y) * b2f(fm.y);
        aq0 = fmaf(b2f(xq.x), b2f(fq.x), aq0);
        aq1 = fmaf(b2f(xq.y), b2f(fq.y), aq1);
        a00 = fmaf(u0, xrs0, a00); a00 = fmaf(b2f(m0.x), xms0, a00);
        a01 = fmaf(u0, xrs1, a01); a01 = fmaf(b2f(m0.y), xms1, a01);
        a10 = fmaf(u1, xrs0, a10); a10 = fmaf(b2f(m1.x), xms0, a10);
        a11 = fmaf(u1, xrs1, a11); a11 = fmaf(b2f(m1.y), xms1, a11);
        a20 = fmaf(u2, xrs0, a20); a20 = fmaf(b2f(m2.x), xms0, a20);
        a21 = fmaf(u2, xrs1, a21); a21 = fmaf(b2f(m2.y), xms1, a21);
    }
    red_s[g * 4 + 0][c2] = aq0; red_s[g * 4 + 0][c2 + 1] = aq1;
    red_s[g * 4 + 1][c2] = a00; red_s[g * 4 + 1][c2 + 1] = a01;
    red_s[g * 4 + 2][c2] = a10; red_s[g * 4 + 2][c2 + 1] = a11;
    red_s[g * 4 + 3][c2] = a20; red_s[g * 4 + 3][c2 + 1] = a21;
    __syncthreads();
    if (t < 128) {
        float vq = red_s[0][t] + red_s[4][t] + red_s[8][t] + red_s[12][t];
        float v0 = red_s[1][t] + red_s[5][t] + red_s[9][t] + red_s[13][t];
        float v1 = red_s[2][t] + red_s[6][t] + red_s[10][t] + red_s[14][t];
        float v2 = red_s[3][t] + red_s[7][t] + red_s[11][t] + red_s[15][t];
        acc_q[(size_t)n * H + t] = vq;
        acc_mu[(size_t)n * H3 + t] = v0;
        acc_mu[(size_t)n * H3 + H + t] = v1;
        acc_mu[(size_t)n * H3 + 2 * H + t] = v2;
    }
}

// ---------------------------------------------------------------------------
// Mixing v4 (unchanged from R4): producer-side hi/lo bf16 planes.
// ---------------------------------------------------------------------------
__global__ __launch_bounds__(512, 4) void mix_kernel(
    const float* __restrict__ q, const float* __restrict__ mu,
    const float* __restrict__ acc_q, const float* __restrict__ acc_mu,
    const unsigned short* __restrict__ Bv_hi, const unsigned short* __restrict__ Bv_lo,
    const unsigned short* __restrict__ B1_hi, const unsigned short* __restrict__ B1_lo,
    const unsigned short* __restrict__ B2_hi, const unsigned short* __restrict__ B2_lo,
    const float* __restrict__ b_mix1, const float* __restrict__ b_mix2,
    float* __restrict__ q_out, float* __restrict__ mu_out) {

    __shared__ __align__(16) unsigned short AH_s[64 * 132];
    __shared__ __align__(16) unsigned short AL_s[64 * 132];
    __shared__ __align__(16) float qn_s[16][128];
    __shared__ __align__(16) float inner_s[16][128];
    __shared__ __align__(16) unsigned short muw_s[48][136];

    const int t = threadIdx.x;
    const int wv = t >> 6, lane = t & 63;
    const int m = lane & 15, qd = lane >> 4;
    const int n0 = blockIdx.x * 16;

    // ---- P0: stage qn (f32 + regs) and equivariant A as hi/lo planes
    float4 qv;
    {
        int r = t >> 5, c4 = (t & 31) * 4;
        float4 a = *(const float4*)&q[(size_t)(n0 + r) * H + c4];
        float4 b = *(const float4*)&acc_q[(size_t)(n0 + r) * H + c4];
        qv.x = a.x + b.x; qv.y = a.y + b.y; qv.z = a.z + b.z; qv.w = a.w + b.w;
        *(float4*)&qn_s[r][c4] = qv;
    }
    for (int i = t; i < 64 * 32; i += 512) {
        int r = i >> 5, c4 = (i & 31) * 4;
        int n = r >> 2, d = r & 3;
        float v[4];
        if (d < 3) {
            float4 a = *(const float4*)&mu[((size_t)(n0 + n) * 3 + d) * H + c4];
            float4 b = *(const float4*)&acc_mu[(size_t)(n0 + n) * H3 + d * H + c4];
            v[0] = a.x + b.x; v[1] = a.y + b.y; v[2] = a.z + b.z; v[3] = a.w + b.w;
        } else { v[0] = v[1] = v[2] = v[3] = 0.f; }
        unsigned short hh[4], ll[4];
        #pragma unroll
        for (int j = 0; j < 4; j++) {
            hh[j] = f2b(v[j]);
            ll[j] = f2b(v[j] - b2f(hh[j]));
        }
        *(ushort4*)&AH_s[r * 132 + c4] = *(ushort4*)&hh[0];
        *(ushort4*)&AL_s[r * 132 + c4] = *(ushort4*)&ll[0];
    }
    __syncthreads();

    // ---- P1: equivariant linear (hi/lo), norm/inner/muw epilogue
    {
        const int rt = wv >> 1, pp = wv & 1;
        const int node = rt * 4 + qd;
        bf16x8 ah[4], al[4];
        #pragma unroll
        for (int kt = 0; kt < 4; kt++) {
            ah[kt] = *(const bf16x8*)&AH_s[(rt * 16 + m) * 132 + qd * 8 + kt * 32];
            al[kt] = *(const bf16x8*)&AL_s[(rt * 16 + m) * 132 + qd * 8 + kt * 32];
        }
        __syncthreads();   // fragments in regs; planes switch to mlp1 layout

        // qn -> mlp1 planes cols [0,128) (same thread mapping as P0 staging)
        {
            int r = t >> 5, c4 = (t & 31) * 4;
            float v[4] = {qv.x, qv.y, qv.z, qv.w};
            unsigned short hh[4], ll[4];
            #pragma unroll
            for (int j = 0; j < 4; j++) {
                hh[j] = f2b(v[j]);
                ll[j] = f2b(v[j] - b2f(hh[j]));
            }
            *(ushort4*)&AH_s[r * 264 + c4] = *(ushort4*)&hh[0];
            *(ushort4*)&AL_s[r * 264 + c4] = *(ushort4*)&ll[0];
        }

        #pragma unroll 1
        for (int jj = 0; jj < 4; jj++) {
            int ctv = 2 * jj + pp;
            f32x4 av = {0.f, 0.f, 0.f, 0.f};
            f32x4 aw = {0.f, 0.f, 0.f, 0.f};
            #pragma unroll
            for (int kt = 0; kt < 4; kt++) {
                size_t bov = ((size_t)(ctv * 4 + kt) * 64 + lane) * 8;
                size_t bow = ((size_t)((ctv + 8) * 4 + kt) * 64 + lane) * 8;
                bf16x8 bvh = *(const bf16x8*)(Bv_hi + bov);
                bf16x8 bvl = *(const bf16x8*)(Bv_lo + bov);
                bf16x8 bwh = *(const bf16x8*)(Bv_hi + bow);
                bf16x8 bwl = *(const bf16x8*)(Bv_lo + bow);
                av = __builtin_amdgcn_mfma_f32_16x16x32_bf16(al[kt], bvh, av, 0, 0, 0);
                av = __builtin_amdgcn_mfma_f32_16x16x32_bf16(ah[kt], bvl, av, 0, 0, 0);
                av = __builtin_amdgcn_mfma_f32_16x16x32_bf16(ah[kt], bvh, av, 0, 0, 0);
                aw = __builtin_amdgcn_mfma_f32_16x16x32_bf16(al[kt], bwh, aw, 0, 0, 0);
                aw = __builtin_amdgcn_mfma_f32_16x16x32_bf16(ah[kt], bwl, aw, 0, 0, 0);
                aw = __builtin_amdgcn_mfma_f32_16x16x32_bf16(ah[kt], bwh, aw, 0, 0, 0);
            }
            int cw = ctv * 16 + m;
            float v0 = av[0], v1 = av[1], v2 = av[2];
            float w0 = aw[0], w1 = aw[1], w2 = aw[2];
            float nv = sqrtf(v0 * v0 + v1 * v1 + v2 * v2 + 1e-8f);
            unsigned short nh = f2b(nv);
            AH_s[node * 264 + 128 + cw] = nh;
            AL_s[node * 264 + 128 + cw] = f2b(nv - b2f(nh));
            inner_s[node][cw] = v0 * w0 + v1 * w1 + v2 * w2;
            muw_s[node * 3 + 0][cw] = f2b(w0);
            muw_s[node * 3 + 1][cw] = f2b(w1);
            muw_s[node * 3 + 2][cw] = f2b(w2);
        }
    }
    __syncthreads();

    // ---- P2: mlp1 (A = [16][264] planes)
    f32x4 hacc[3] = {{0.f,0.f,0.f,0.f},{0.f,0.f,0.f,0.f},{0.f,0.f,0.f,0.f}};
    #pragma unroll 1
    for (int half = 0; half < 2; half++) {
        bf16x8 ah[4], al[4];
        #pragma unroll
        for (int u = 0; u < 4; u++) {
            ah[u] = *(const bf16x8*)&AH_s[m * 264 + half * 128 + qd * 8 + u * 32];
            al[u] = *(const bf16x8*)&AL_s[m * 264 + half * 128 + qd * 8 + u * 32];
        }
        #pragma unroll
        for (int jj = 0; jj < 3; jj++) {
            int ct = jj * 8 + wv;
            #pragma unroll
            for (int u = 0; u < 4; u++) {
                int kt = half * 4 + u;
                size_t bo = ((size_t)(ct * 8 + kt) * 64 + lane) * 8;
                bf16x8 bh = *(const bf16x8*)(B1_hi + bo);
                bf16x8 bl = *(const bf16x8*)(B1_lo + bo);
                hacc[jj] = __builtin_amdgcn_mfma_f32_16x16x32_bf16(al[u], bh, hacc[jj], 0, 0, 0);
                hacc[jj] = __builtin_amdgcn_mfma_f32_16x16x32_bf16(ah[u], bl, hacc[jj], 0, 0, 0);
                hacc[jj] = __builtin_amdgcn_mfma_f32_16x16x32_bf16(ah[u], bh, hacc[jj], 0, 0, 0);
            }
        }
    }
    __syncthreads();   // planes dead -> mlp2 layout

    // ---- P3: silu epilogue -> mlp2 planes [16][392]
    #pragma unroll
    for (int jj = 0; jj < 3; jj++) {
        int ct = jj * 8 + wv;
        int c = ct * 16 + m;
        float bb = b_mix1[c];
        #pragma unroll
        for (int r = 0; r < 4; r++) {
            int node = qd * 4 + r;
            float sv = silu_f(hacc[jj][r] + bb);
            unsigned short sh = f2b(sv);
            AH_s[node * 392 + c] = sh;
            AL_s[node * 392 + c] = f2b(sv - b2f(sh));
        }
    }
    __syncthreads();

    // ---- P4: mlp2 (A = [16][392] planes) + final epilogue
    {
        f32x4 dacc[3] = {{0.f,0.f,0.f,0.f},{0.f,0.f,0.f,0.f},{0.f,0.f,0.f,0.f}};
        #pragma unroll 1
        for (int half = 0; half < 2; half++) {
            bf16x8 ah[6], al[6];
            #pragma unroll
            for (int u = 0; u < 6; u++) {
                ah[u] = *(const bf16x8*)&AH_s[m * 392 + half * 192 + qd * 8 + u * 32];
                al[u] = *(const bf16x8*)&AL_s[m * 392 + half * 192 + qd * 8 + u * 32];
            }
            #pragma unroll
            for (int jj = 0; jj < 3; jj++) {
                int ct = jj * 8 + wv;
                #pragma unroll
                for (int u = 0; u < 6; u++) {
                    int kt = half * 6 + u;
                    size_t bo = ((size_t)(ct * 12 + kt) * 64 + lane) * 8;
                    bf16x8 bh = *(const bf16x8*)(B2_hi + bo);
                    bf16x8 bl = *(const bf16x8*)(B2_lo + bo);
                    dacc[jj] = __builtin_amdgcn_mfma_f32_16x16x32_bf16(al[u], bh, dacc[jj], 0, 0, 0);
                    dacc[jj] = __builtin_amdgcn_mfma_f32_16x16x32_bf16(ah[u], bl, dacc[jj], 0, 0, 0);
                    dacc[jj] = __builtin_amdgcn_mfma_f32_16x16x32_bf16(ah[u], bh, dacc[jj], 0, 0, 0);
                }
            }
        }
        const int c = wv * 16 + m;
        float bq = b_mix2[c], bs = b_mix2[128 + c], bu = b_mix2[256 + c];
        #pragma unroll
        for (int r = 0; r < 4; r++) {
            int node = qd * 4 + r;
            float dq   = dacc[0][r] + bq;
            float dms  = dacc[1][r] + bs;
            float dqmu = dacc[2][r] + bu;
            q_out[(size_t)(n0 + node) * H + c] =
                qn_s[node][c] + dq + dqmu * inner_s[node][c];
            #pragma unroll
            for (int d = 0; d < 3; d++) {
                size_t gi = ((size_t)(n0 + node) * 3 + d) * H + c;
                float mun = mu[gi] + acc_mu[(size_t)(n0 + node) * H3 + d * H + c];
                mu_out[gi] = mun + b2f(muw_s[node * 3 + d][c]) * dms;
            }
        }
    }
}

extern "C" void kernel_launch(void* const* d_in, const int* in_sizes, int n_in,
                              void* d_out, int out_size, void* d_ws, size_t ws_size,
                              hipStream_t stream) {
    const float* q        = (const float*)d_in[0];
    const float* mu       = (const float*)d_in[1];
    const int*   eidx     = (const int*)d_in[2];
    const float* rbf      = (const float*)d_in[3];
    const float* unitv    = (const float*)d_in[4];
    const float* cutoff   = (const float*)d_in[5];
    const float* W_inter1 = (const float*)d_in[6];
    const float* b_inter1 = (const float*)d_in[7];
    const float* W_inter2 = (const float*)d_in[8];
    const float* b_inter2 = (const float*)d_in[9];
    const float* W_filt1  = (const float*)d_in[10];
    const float* b_filt1  = (const float*)d_in[11];
    const float* W_filt2  = (const float*)d_in[12];
    const float* b_filt2  = (const float*)d_in[13];
    const float* W_vec    = (const float*)d_in[14];
    const float* W_mix1   = (const float*)d_in[15];
    const float* b_mix1   = (const float*)d_in[16];
    const float* W_mix2   = (const float*)d_in[17];
    const float* b_mix2   = (const float*)d_in[18];

    // workspace layout
    char* p = (char*)d_ws;
    float* acc_q       = (float*)p;            p += (size_t)NN * H * 4;
    float* acc_mu      = (float*)p;            p += (size_t)NN * H3 * 4;
    float* sorted_unit = (float*)p;            p += (size_t)NE * 3 * 4;
    int*   counts      = (int*)p;              p += (size_t)NN * 4;
    int*   off         = (int*)p;              p += (size_t)(NN + 1) * 4;
    p = (char*)(((size_t)p + 255) & ~(size_t)255);
    int*   cursor      = (int*)p;              p += (size_t)NN * 4;
    p = (char*)(((size_t)p + 255) & ~(size_t)255);
    int*   sorted_eid  = (int*)p;              p += (size_t)NE * 4;
    int*   sorted_src  = (int*)p;              p += (size_t)NE * 4;
    p = (char*)(((size_t)p + 255) & ~(size_t)255);
    unsigned short* Bp    = (unsigned short*)p; p += (size_t)H * H3 * 2;
    unsigned short* Bp1   = (unsigned short*)p; p += (size_t)H * H3 * 2;
    unsigned short* Bp2   = (unsigned short*)p; p += (size_t)H3 * H3 * 2;
    unsigned short* Bf1p  = (unsigned short*)p; p += (size_t)8 * 64 * 8 * 2;
    unsigned short* Bv_hi = (unsigned short*)p; p += (size_t)H * H2 * 2;
    unsigned short* Bv_lo = (unsigned short*)p; p += (size_t)H * H2 * 2;
    unsigned short* B1_hi = (unsigned short*)p; p += (size_t)H2 * H3 * 2;
    unsigned short* B1_lo = (unsigned short*)p; p += (size_t)H2 * H3 * 2;
    unsigned short* B2_hi = (unsigned short*)p; p += (size_t)H3 * H3 * 2;
    unsigned short* B2_lo = (unsigned short*)p; p += (size_t)H3 * H3 * 2;
    p = (char*)(((size_t)p + 255) & ~(size_t)255);
    unsigned short* x_b  = (unsigned short*)p;  p += (size_t)NN * H3 * 2;
    unsigned short* mu_b = (unsigned short*)p;  p += (size_t)NN * H3 * 2;
    p = (char*)(((size_t)p + 255) & ~(size_t)255);
    unsigned short* filt = (unsigned short*)p;  p += (size_t)NE * H3 * 2;

    float* q_out  = (float*)d_out;
    float* mu_out = q_out + (size_t)NN * H;

    hipMemsetAsync(counts, 0, (size_t)NN * 4, stream);

    hist_kernel    <<<NE / 256, 256, 0, stream>>>(eidx, counts);
    pack_all_kernel<<<1032, 64, 0, stream>>>(W_filt2, W_inter1, W_inter2, W_filt1,
                                             W_vec, W_mix1, W_mix2,
                                             Bp, Bp1, Bp2, Bf1p,
                                             Bv_hi, Bv_lo, B1_hi, B1_lo, B2_hi, B2_lo);
    scan_kernel    <<<1, 1024, 0, stream>>>(counts, off, cursor);
    place_kernel   <<<NE / 256, 256, 0, stream>>>(eidx, unitv, cursor,
                                                  sorted_eid, sorted_src, sorted_unit);
    node_x_kernel  <<<(NN + 31) / 32, 256, 0, stream>>>(q, Bp1, b_inter1, Bp2, b_inter2, x_b);
    mu2b_kernel    <<<NN * H3 / (4 * 256), 256, 0, stream>>>(mu, mu_b);
    filter_kernel  <<<NE / 64, 256, 0, stream>>>(rbf, cutoff, Bf1p, b_filt1,
                                                 Bp, b_filt2, filt);
    gather_kernel  <<<NN, 256, 0, stream>>>(off, sorted_eid, sorted_src, sorted_unit,
                                            filt, x_b, mu_b, acc_q, acc_mu);
    mix_kernel     <<<NN / 16, 512, 0, stream>>>(q, mu, acc_q, acc_mu,
                                                 Bv_hi, Bv_lo, B1_hi, B1_lo, B2_hi, B2_lo,
                                                 b_mix1, b_mix2, q_out, mu_out);
}

// Round 8
// 439.082 us; speedup vs baseline: 1.0241x; 1.0241x over previous
//
#include <hip/hip_runtime.h>

#define NN 10000
#define NE 256000
#define H 128
#define H2 256
#define H3 384
#define NRBF 20

typedef __attribute__((ext_vector_type(8))) short bf16x8;
typedef __attribute__((ext_vector_type(4))) float f32x4;

__device__ __forceinline__ float silu_f(float v) { return v / (1.f + __expf(-v)); }

// fp32 -> bf16 bits (RNE)
__device__ __forceinline__ unsigned short f2b(float f) {
    union { float f; unsigned u; } x; x.f = f;
    unsigned r = (x.u + 0x7FFFu + ((x.u >> 16) & 1u)) >> 16;
    return (unsigned short)r;
}
__device__ __forceinline__ float b2f(unsigned short b) {
    union { unsigned u; float f; } x; x.u = ((unsigned)b) << 16;
    return x.f;
}

// packed RNE f32x2 -> bf16x2 (1 VALU op; bit-identical to f2b pair)
__device__ __forceinline__ unsigned cvtpk(float lo, float hi) {
    unsigned r;
    asm("v_cvt_pk_bf16_f32 %0, %1, %2" : "=v"(r) : "v"(lo), "v"(hi));
    return r;
}
// hi/lo split of a value pair into packed hi-plane / lo-plane words
__device__ __forceinline__ void split_pair(float v0, float v1, unsigned &ph, unsigned &pl) {
    ph = cvtpk(v0, v1);
    union { unsigned u; float f; } a, b;
    a.u = ph << 16;            // bf16(v0) as f32 bits
    b.u = ph & 0xFFFF0000u;    // bf16(v1) as f32 bits
    pl = cvtpk(v0 - a.f, v1 - b.f);
}

// ---------------------------------------------------------------------------
// CSR build
// ---------------------------------------------------------------------------
__global__ __launch_bounds__(256) void hist_kernel(const int* __restrict__ eidx,
                                                   int* __restrict__ counts) {
    int e = blockIdx.x * 256 + threadIdx.x;
    atomicAdd(&counts[eidx[e]], 1);
}

__global__ __launch_bounds__(1024) void scan_kernel(const int* __restrict__ counts,
                                                    int* __restrict__ off,
                                                    int* __restrict__ cursor) {
    __shared__ int sums[1024];
    const int t = threadIdx.x;
    const int base = t * 10;
    int local[10];
    int s = 0;
    #pragma unroll
    for (int i = 0; i < 10; i++) {
        int idx = base + i;
        int v = (idx < NN) ? counts[idx] : 0;
        local[i] = s; s += v;
    }
    sums[t] = s;
    __syncthreads();
    for (int d = 1; d < 1024; d <<= 1) {
        int v = (t >= d) ? sums[t - d] : 0;
        __syncthreads();
        sums[t] += v;
        __syncthreads();
    }
    int prefix = (t > 0) ? sums[t - 1] : 0;
    #pragma unroll
    for (int i = 0; i < 10; i++) {
        int idx = base + i;
        if (idx < NN) { off[idx] = prefix + local[i]; cursor[idx] = prefix + local[i]; }
    }
    if (t == 1023) off[NN] = sums[1023];
}

__global__ __launch_bounds__(256) void place_kernel(
    const int* __restrict__ eidx, const float* __restrict__ unitv,
    int* __restrict__ cursor, int* __restrict__ sorted_eid,
    int* __restrict__ sorted_src, float* __restrict__ sorted_unit) {
    int e = blockIdx.x * 256 + threadIdx.x;
    int tgt = eidx[e];
    int src = eidx[NE + e];
    int pos = atomicAdd(&cursor[tgt], 1);
    sorted_eid[pos] = e;
    sorted_src[pos] = src;
    sorted_unit[pos * 3 + 0] = unitv[(size_t)e * 3 + 0];
    sorted_unit[pos * 3 + 1] = unitv[(size_t)e * 3 + 1];
    sorted_unit[pos * 3 + 2] = unitv[(size_t)e * 3 + 2];
}

// ---------------------------------------------------------------------------
// Unified weight packing (one launch). 64-thread blocks, range-switched.
// ---------------------------------------------------------------------------
__device__ __forceinline__ void pack_hi_one(const float* __restrict__ W, int K, int N,
                                            unsigned short* __restrict__ dst,
                                            int b, int lane) {
    const int KT = K >> 5;
    const int kt = b % KT, ct = b / KT;
    const int m = lane & 15, qd = lane >> 4;
    size_t base = ((size_t)(ct * KT + kt) * 64 + lane) * 8;
    unsigned short v[8];
    #pragma unroll
    for (int j = 0; j < 8; j++) {
        int k = kt * 32 + qd * 8 + j;
        v[j] = f2b(W[(size_t)k * N + ct * 16 + m]);
    }
    *(ushort4*)&dst[base]     = *(ushort4*)&v[0];
    *(ushort4*)&dst[base + 4] = *(ushort4*)&v[4];
}

__device__ __forceinline__ void pack_split_one(const float* __restrict__ W, int K, int N,
                                               unsigned short* __restrict__ hi,
                                               unsigned short* __restrict__ lo,
                                               int b, int lane) {
    const int KT = K >> 5;
    const int kt = b % KT, ct = b / KT;
    const int m = lane & 15, qd = lane >> 4;
    size_t base = ((size_t)(ct * KT + kt) * 64 + lane) * 8;
    #pragma unroll
    for (int j = 0; j < 8; j++) {
        int k = kt * 32 + qd * 8 + j;
        float v = W[(size_t)k * N + ct * 16 + m];
        unsigned short h = f2b(v);
        hi[base + j] = h;
        lo[base + j] = f2b(v - b2f(h));
    }
}

__global__ __launch_bounds__(64) void pack_all_kernel(
    const float* __restrict__ Wf2, const float* __restrict__ Wi1,
    const float* __restrict__ Wi2, const float* __restrict__ Wf1,
    const float* __restrict__ Wv, const float* __restrict__ Wm1,
    const float* __restrict__ Wm2,
    unsigned short* __restrict__ Bp, unsigned short* __restrict__ Bp1,
    unsigned short* __restrict__ Bp2, unsigned short* __restrict__ Bf1p,
    unsigned short* __restrict__ Bv_hi, unsigned short* __restrict__ Bv_lo,
    unsigned short* __restrict__ B1_hi, unsigned short* __restrict__ B1_lo,
    unsigned short* __restrict__ B2_hi, unsigned short* __restrict__ B2_lo) {
    const int b = blockIdx.x;
    const int lane = threadIdx.x;
    if (b < 96)        pack_hi_one(Wf2, H, H3, Bp, b, lane);
    else if (b < 192)  pack_hi_one(Wi1, H, H3, Bp1, b - 96, lane);
    else if (b < 480)  pack_hi_one(Wi2, H3, H3, Bp2, b - 192, lane);
    else if (b < 488) {                               // Wf1: K=20 zero-padded to 32
        const int ct = b - 480;
        const int m = lane & 15, qd = lane >> 4;
        size_t base = ((size_t)ct * 64 + lane) * 8;
        unsigned short v[8];
        #pragma unroll
        for (int j = 0; j < 8; j++) {
            int k = qd * 8 + j;
            v[j] = (k < NRBF) ? f2b(Wf1[(size_t)k * H + ct * 16 + m]) : (unsigned short)0;
        }
        *(ushort4*)&Bf1p[base]     = *(ushort4*)&v[0];
        *(ushort4*)&Bf1p[base + 4] = *(ushort4*)&v[4];
    }
    else if (b < 552)  pack_split_one(Wv,  H,  H2, Bv_hi, Bv_lo, b - 488, lane);
    else if (b < 744)  pack_split_one(Wm1, H2, H3, B1_hi, B1_lo, b - 552, lane);
    else if (b < 1032) pack_split_one(Wm2, H3, H3, B2_hi, B2_lo, b - 744, lane);
}

// mu fp32 -> bf16 copy (cvt_pk)
__global__ __launch_bounds__(256) void mu2b_kernel(const float* __restrict__ mu,
                                                   unsigned short* __restrict__ mu_b) {
    int i = blockIdx.x * 256 + threadIdx.x;
    float4 v = ((const float4*)mu)[i];
    uint2 o;
    o.x = cvtpk(v.x, v.y);
    o.y = cvtpk(v.z, v.w);
    ((uint2*)mu_b)[i] = o;
}

// ---------------------------------------------------------------------------
// node_x (MFMA): x_b = bf16(silu(q@W1+b1) @ W2 + b2). 32 nodes per block.
// v2: cvt_pk conversions in staging + epilogues (VALU cut).
// ---------------------------------------------------------------------------
__global__ __launch_bounds__(256) void node_x_kernel(
    const float* __restrict__ q,
    const unsigned short* __restrict__ Bp1, const float* __restrict__ b1,
    const unsigned short* __restrict__ Bp2, const float* __restrict__ b2,
    unsigned short* __restrict__ x_b) {
    __shared__ __align__(16) unsigned short qa_s[32 * 136];
    __shared__ __align__(16) unsigned short h1_s[32 * 392];
    const int t = threadIdx.x;
    const int wv = t >> 6, lane = t & 63;
    const int m = lane & 15, qd = lane >> 4;
    const int st = wv >> 1, ch = wv & 1;
    const int n0 = blockIdx.x * 32;

    for (int i = t; i < 32 * 32; i += 256) {
        int r = i >> 5, c4 = (i & 31) * 4;
        int node = n0 + r;
        uint2 o;
        if (node < NN) {
            float4 v = *(const float4*)&q[(size_t)node * H + c4];
            o.x = cvtpk(v.x, v.y);
            o.y = cvtpk(v.z, v.w);
        } else { o.x = o.y = 0; }
        *(uint2*)&qa_s[r * 136 + c4] = o;
    }
    __syncthreads();

    {
        const unsigned short* arow = &qa_s[(st * 16 + m) * 136 + qd * 8];
        #pragma unroll 1
        for (int jc = 0; jc < 12; jc++) {
            int ct = ch * 12 + jc;
            f32x4 acc = {0.f, 0.f, 0.f, 0.f};
            #pragma unroll
            for (int kt = 0; kt < 4; kt++) {
                bf16x8 af = *(const bf16x8*)(arow + kt * 32);
                bf16x8 bfr = *(const bf16x8*)(Bp1 + ((size_t)(ct * 4 + kt) * 64 + lane) * 8);
                acc = __builtin_amdgcn_mfma_f32_16x16x32_bf16(af, bfr, acc, 0, 0, 0);
            }
            int col = ct * 16 + m;
            float bb = b1[col];
            unsigned p01 = cvtpk(silu_f(acc[0] + bb), silu_f(acc[1] + bb));
            unsigned p23 = cvtpk(silu_f(acc[2] + bb), silu_f(acc[3] + bb));
            int rb = st * 16 + qd * 4;
            h1_s[(rb + 0) * 392 + col] = (unsigned short)(p01 & 0xFFFFu);
            h1_s[(rb + 1) * 392 + col] = (unsigned short)(p01 >> 16);
            h1_s[(rb + 2) * 392 + col] = (unsigned short)(p23 & 0xFFFFu);
            h1_s[(rb + 3) * 392 + col] = (unsigned short)(p23 >> 16);
        }
    }
    __syncthreads();

    {
        const unsigned short* arow = &h1_s[(st * 16 + m) * 392 + qd * 8];
        #pragma unroll 1
        for (int jc = 0; jc < 12; jc++) {
            int ct = ch * 12 + jc;
            f32x4 acc = {0.f, 0.f, 0.f, 0.f};
            #pragma unroll
            for (int kt = 0; kt < 12; kt++) {
                bf16x8 af = *(const bf16x8*)(arow + kt * 32);
                bf16x8 bfr = *(const bf16x8*)(Bp2 + ((size_t)(ct * 12 + kt) * 64 + lane) * 8);
                acc = __builtin_amdgcn_mfma_f32_16x16x32_bf16(af, bfr, acc, 0, 0, 0);
            }
            int col = ct * 16 + m;
            float bb = b2[col];
            unsigned p01 = cvtpk(acc[0] + bb, acc[1] + bb);
            unsigned p23 = cvtpk(acc[2] + bb, acc[3] + bb);
            int rb = n0 + st * 16 + qd * 4;
            if (rb + 0 < NN) x_b[(size_t)(rb + 0) * H3 + col] = (unsigned short)(p01 & 0xFFFFu);
            if (rb + 1 < NN) x_b[(size_t)(rb + 1) * H3 + col] = (unsigned short)(p01 >> 16);
            if (rb + 2 < NN) x_b[(size_t)(rb + 2) * H3 + col] = (unsigned short)(p23 & 0xFFFFu);
            if (rb + 3 < NN) x_b[(size_t)(rb + 3) * H3 + col] = (unsigned short)(p23 >> 16);
        }
    }
}

// ---------------------------------------------------------------------------
// Filter MLP v9: v7 structure (measured best, 87us) + cvt_pk VALU cuts in
// L1 af-build and h1 epilogue. R6 lesson: LDS/occupancy was NOT binding
// (26KB LDS left occupancy at 28%); VALU op count is the largest measured
// consumer (VALUBusy 42% ~= static epilogue op count).
// ---------------------------------------------------------------------------
__global__ __launch_bounds__(256) void filter_kernel(
    const float* __restrict__ rbf, const float* __restrict__ cutoff,
    const unsigned short* __restrict__ Bf1p, const float* __restrict__ bf1,
    const unsigned short* __restrict__ Bp, const float* __restrict__ bf2,
    unsigned short* __restrict__ filt) {
    __shared__ __align__(16) char raw_s[64 * 392 * 2];   // 50176 B union
    __shared__ float cut_s[64];
    float (*rbf_s)[21] = (float (*)[21])raw_s;                             // L1 input
    unsigned short (*h1_s)[136] = (unsigned short (*)[136])(raw_s + 5376); // L1 output
    unsigned short (*out_s)[392] = (unsigned short (*)[392])raw_s;         // L2 output

    const int t = threadIdx.x;
    const int wv = t >> 6, lane = t & 63;
    const int m = lane & 15, qd = lane >> 4;
    const size_t e0 = (size_t)blockIdx.x * 64;

    if (t < 64) cut_s[t] = cutoff[e0 + t];
    for (int i = t; i < 64 * NRBF; i += 256) {          // coalesced
        rbf_s[i / NRBF][i % NRBF] = rbf[e0 * NRBF + i];
    }
    __syncthreads();

    // layer 1 MFMA: wave wv owns slot-tile wv (rows wv*16..wv*16+15)
    {
        bf16x8 af;
        {
            union { unsigned u[4]; bf16x8 v; } cu;
            #pragma unroll
            for (int i = 0; i < 4; i++) {
                int k0 = qd * 8 + 2 * i;
                float v0 = (k0 < NRBF) ? rbf_s[wv * 16 + m][k0] : 0.f;
                float v1 = (k0 + 1 < NRBF) ? rbf_s[wv * 16 + m][k0 + 1] : 0.f;
                cu.u[i] = cvtpk(v0, v1);
            }
            af = cu.v;
        }
        #pragma unroll
        for (int ct = 0; ct < 8; ct++) {
            f32x4 acc = {0.f, 0.f, 0.f, 0.f};
            bf16x8 bfr = *(const bf16x8*)(Bf1p + ((size_t)ct * 64 + lane) * 8);
            acc = __builtin_amdgcn_mfma_f32_16x16x32_bf16(af, bfr, acc, 0, 0, 0);
            int col = ct * 16 + m;
            float bb = bf1[col];
            unsigned p01 = cvtpk(silu_f(acc[0] + bb), silu_f(acc[1] + bb));
            unsigned p23 = cvtpk(silu_f(acc[2] + bb), silu_f(acc[3] + bb));
            int rb = wv * 16 + qd * 4;
            h1_s[rb + 0][col] = (unsigned short)(p01 & 0xFFFFu);
            h1_s[rb + 1][col] = (unsigned short)(p01 >> 16);
            h1_s[rb + 2][col] = (unsigned short)(p23 & 0xFFFFu);
            h1_s[rb + 3][col] = (unsigned short)(p23 >> 16);
        }
    }
    __syncthreads();

    // layer 2: wave wv -> cols [wv*96, wv*96+96), all 64 edge rows.
    {
        bf16x8 hfr[4][4];
        #pragma unroll
        for (int et = 0; et < 4; et++) {
            #pragma unroll
            for (int kt = 0; kt < 4; kt++) {
                hfr[et][kt] = *(const bf16x8*)&h1_s[et * 16 + m][qd * 8 + kt * 32];
            }
        }
        float cutv[4];
        #pragma unroll
        for (int et = 0; et < 4; et++) cutv[et] = cut_s[et * 16 + m];
        __syncthreads();   // all waves done reading h1_s -> raw_s becomes out_s

        #pragma unroll
        for (int cc = 0; cc < 6; cc++) {
            const int ct = wv * 6 + cc;
            bf16x8 w0 = *(const bf16x8*)(Bp + ((size_t)(ct * 4 + 0) * 64 + lane) * 8);
            bf16x8 w1 = *(const bf16x8*)(Bp + ((size_t)(ct * 4 + 1) * 64 + lane) * 8);
            bf16x8 w2 = *(const bf16x8*)(Bp + ((size_t)(ct * 4 + 2) * 64 + lane) * 8);
            bf16x8 w3 = *(const bf16x8*)(Bp + ((size_t)(ct * 4 + 3) * 64 + lane) * 8);
            f32x4 acc0 = {0.f, 0.f, 0.f, 0.f};
            f32x4 acc1 = {0.f, 0.f, 0.f, 0.f};
            f32x4 acc2 = {0.f, 0.f, 0.f, 0.f};
            f32x4 acc3 = {0.f, 0.f, 0.f, 0.f};
            acc0 = __builtin_amdgcn_mfma_f32_16x16x32_bf16(w0, hfr[0][0], acc0, 0, 0, 0);
            acc1 = __builtin_amdgcn_mfma_f32_16x16x32_bf16(w0, hfr[1][0], acc1, 0, 0, 0);
            acc2 = __builtin_amdgcn_mfma_f32_16x16x32_bf16(w0, hfr[2][0], acc2, 0, 0, 0);
            acc3 = __builtin_amdgcn_mfma_f32_16x16x32_bf16(w0, hfr[3][0], acc3, 0, 0, 0);
            acc0 = __builtin_amdgcn_mfma_f32_16x16x32_bf16(w1, hfr[0][1], acc0, 0, 0, 0);
            acc1 = __builtin_amdgcn_mfma_f32_16x16x32_bf16(w1, hfr[1][1], acc1, 0, 0, 0);
            acc2 = __builtin_amdgcn_mfma_f32_16x16x32_bf16(w1, hfr[2][1], acc2, 0, 0, 0);
            acc3 = __builtin_amdgcn_mfma_f32_16x16x32_bf16(w1, hfr[3][1], acc3, 0, 0, 0);
            acc0 = __builtin_amdgcn_mfma_f32_16x16x32_bf16(w2, hfr[0][2], acc0, 0, 0, 0);
            acc1 = __builtin_amdgcn_mfma_f32_16x16x32_bf16(w2, hfr[1][2], acc1, 0, 0, 0);
            acc2 = __builtin_amdgcn_mfma_f32_16x16x32_bf16(w2, hfr[2][2], acc2, 0, 0, 0);
            acc3 = __builtin_amdgcn_mfma_f32_16x16x32_bf16(w2, hfr[3][2], acc3, 0, 0, 0);
            acc0 = __builtin_amdgcn_mfma_f32_16x16x32_bf16(w3, hfr[0][3], acc0, 0, 0, 0);
            acc1 = __builtin_amdgcn_mfma_f32_16x16x32_bf16(w3, hfr[1][3], acc1, 0, 0, 0);
            acc2 = __builtin_amdgcn_mfma_f32_16x16x32_bf16(w3, hfr[2][3], acc2, 0, 0, 0);
            acc3 = __builtin_amdgcn_mfma_f32_16x16x32_bf16(w3, hfr[3][3], acc3, 0, 0, 0);

            float4 bb = *(const float4*)&bf2[ct * 16 + qd * 4];
            const int colb = ct * 16 + qd * 4;
            #pragma unroll
            for (int et = 0; et < 4; et++) {
                f32x4 a = (et == 0) ? acc0 : (et == 1) ? acc1 : (et == 2) ? acc2 : acc3;
                float c = cutv[et];
                float o0 = (a[0] + bb.x) * c;
                float o1 = (a[1] + bb.y) * c;
                float o2 = (a[2] + bb.z) * c;
                float o3 = (a[3] + bb.w) * c;
                uint2 st; st.x = cvtpk(o0, o1); st.y = cvtpk(o2, o3);
                *(uint2*)&out_s[et * 16 + m][colb] = st;
            }
        }
    }
    __syncthreads();

    // streaming writeout: 64 rows x 768 B contiguous (48 KB block region)
    #pragma unroll
    for (int i = 0; i < 12; i++) {
        int u = i * 256 + t;
        int row = u / 48, c16 = u % 48;
        *(uint4*)&filt[(e0 + row) * H3 + c16 * 8] = *(const uint4*)&out_s[row][c16 * 8];
    }
}

// ---------------------------------------------------------------------------
// Gather: filt indexed through sorted_eid (filter runs in original order).
// ---------------------------------------------------------------------------
__global__ __launch_bounds__(256) void gather_kernel(
    const int* __restrict__ off, const int* __restrict__ sorted_eid,
    const int* __restrict__ sorted_src, const float* __restrict__ sorted_unit,
    const unsigned short* __restrict__ filt,
    const unsigned short* __restrict__ x_b, const unsigned short* __restrict__ mu_b,
    float* __restrict__ acc_q, float* __restrict__ acc_mu) {
    __shared__ float red_s[16][128];
    const int t = threadIdx.x;
    const int n = blockIdx.x;
    const int g = t >> 6, lane = t & 63;
    const int c2 = lane * 2;
    const int j0 = off[n], j1 = off[n + 1];

    float aq0 = 0.f, aq1 = 0.f, a00 = 0.f, a01 = 0.f;
    float a10 = 0.f, a11 = 0.f, a20 = 0.f, a21 = 0.f;
    for (int j = j0 + g; j < j1; j += 4) {
        int e = sorted_eid[j];
        int src = sorted_src[j];
        float u0 = sorted_unit[j * 3 + 0];
        float u1 = sorted_unit[j * 3 + 1];
        float u2 = sorted_unit[j * 3 + 2];
        const unsigned short* frow = filt + (size_t)e * H3 + c2;
        const unsigned short* xrow = x_b + (size_t)src * H3 + c2;
        const unsigned short* murow = mu_b + (size_t)src * H3 + c2;
        ushort2 fq = *(const ushort2*)(frow);
        ushort2 fr = *(const ushort2*)(frow + H);
        ushort2 fm = *(const ushort2*)(frow + 2 * H);
        ushort2 xq = *(const ushort2*)(xrow);
        ushort2 xr = *(const ushort2*)(xrow + H);
        ushort2 xm = *(const ushort2*)(xrow + 2 * H);
        ushort2 m0 = *(const ushort2*)(murow);
        ushort2 m1 = *(const ushort2*)(murow + H);
        ushort2 m2 = *(const ushort2*)(murow + 2 * H);
        float xrs0 = b2f(xr.x) * b2f(fr.x), xrs1 = b2f(xr.y) * b2f(fr.y);
        float xms0 = b2f(xm.x) * b2f(fm.x), xms1 = b2f(xm.y) * b2f(fm.y);
        aq0 = fmaf(b2f(xq.x), b2f(fq.x), aq0);
        aq1 = fmaf(b2f(xq.y), b2f(fq.y), aq1);
        a00 = fmaf(u0, xrs0, a00); a00 = fmaf(b2f(m0.x), xms0, a00);
        a01 = fmaf(u0, xrs1, a01); a01 = fmaf(b2f(m0.y), xms1, a01);
        a10 = fmaf(u1, xrs0, a10); a10 = fmaf(b2f(m1.x), xms0, a10);
        a11 = fmaf(u1, xrs1, a11); a11 = fmaf(b2f(m1.y), xms1, a11);
        a20 = fmaf(u2, xrs0, a20); a20 = fmaf(b2f(m2.x), xms0, a20);
        a21 = fmaf(u2, xrs1, a21); a21 = fmaf(b2f(m2.y), xms1, a21);
    }
    red_s[g * 4 + 0][c2] = aq0; red_s[g * 4 + 0][c2 + 1] = aq1;
    red_s[g * 4 + 1][c2] = a00; red_s[g * 4 + 1][c2 + 1] = a01;
    red_s[g * 4 + 2][c2] = a10; red_s[g * 4 + 2][c2 + 1] = a11;
    red_s[g * 4 + 3][c2] = a20; red_s[g * 4 + 3][c2 + 1] = a21;
    __syncthreads();
    if (t < 128) {
        float vq = red_s[0][t] + red_s[4][t] + red_s[8][t] + red_s[12][t];
        float v0 = red_s[1][t] + red_s[5][t] + red_s[9][t] + red_s[13][t];
        float v1 = red_s[2][t] + red_s[6][t] + red_s[10][t] + red_s[14][t];
        float v2 = red_s[3][t] + red_s[7][t] + red_s[11][t] + red_s[15][t];
        acc_q[(size_t)n * H + t] = vq;
        acc_mu[(size_t)n * H3 + t] = v0;
        acc_mu[(size_t)n * H3 + H + t] = v1;
        acc_mu[(size_t)n * H3 + 2 * H + t] = v2;
    }
}

// ---------------------------------------------------------------------------
// Mixing v5: v4 (producer-side hi/lo planes) + packed split_pair staging.
// ---------------------------------------------------------------------------
__global__ __launch_bounds__(512, 4) void mix_kernel(
    const float* __restrict__ q, const float* __restrict__ mu,
    const float* __restrict__ acc_q, const float* __restrict__ acc_mu,
    const unsigned short* __restrict__ Bv_hi, const unsigned short* __restrict__ Bv_lo,
    const unsigned short* __restrict__ B1_hi, const unsigned short* __restrict__ B1_lo,
    const unsigned short* __restrict__ B2_hi, const unsigned short* __restrict__ B2_lo,
    const float* __restrict__ b_mix1, const float* __restrict__ b_mix2,
    float* __restrict__ q_out, float* __restrict__ mu_out) {

    __shared__ __align__(16) unsigned short AH_s[64 * 132];
    __shared__ __align__(16) unsigned short AL_s[64 * 132];
    __shared__ __align__(16) float qn_s[16][128];
    __shared__ __align__(16) float inner_s[16][128];
    __shared__ __align__(16) unsigned short muw_s[48][136];

    const int t = threadIdx.x;
    const int wv = t >> 6, lane = t & 63;
    const int m = lane & 15, qd = lane >> 4;
    const int n0 = blockIdx.x * 16;

    // ---- P0: stage qn (f32 + regs) and equivariant A as hi/lo planes
    float4 qv;
    {
        int r = t >> 5, c4 = (t & 31) * 4;
        float4 a = *(const float4*)&q[(size_t)(n0 + r) * H + c4];
        float4 b = *(const float4*)&acc_q[(size_t)(n0 + r) * H + c4];
        qv.x = a.x + b.x; qv.y = a.y + b.y; qv.z = a.z + b.z; qv.w = a.w + b.w;
        *(float4*)&qn_s[r][c4] = qv;
    }
    for (int i = t; i < 64 * 32; i += 512) {
        int r = i >> 5, c4 = (i & 31) * 4;
        int n = r >> 2, d = r & 3;
        float v[4];
        if (d < 3) {
            float4 a = *(const float4*)&mu[((size_t)(n0 + n) * 3 + d) * H + c4];
            float4 b = *(const float4*)&acc_mu[(size_t)(n0 + n) * H3 + d * H + c4];
            v[0] = a.x + b.x; v[1] = a.y + b.y; v[2] = a.z + b.z; v[3] = a.w + b.w;
        } else { v[0] = v[1] = v[2] = v[3] = 0.f; }
        unsigned ph01, pl01, ph23, pl23;
        split_pair(v[0], v[1], ph01, pl01);
        split_pair(v[2], v[3], ph23, pl23);
        uint2 h2; h2.x = ph01; h2.y = ph23;
        uint2 l2; l2.x = pl01; l2.y = pl23;
        *(uint2*)&AH_s[r * 132 + c4] = h2;
        *(uint2*)&AL_s[r * 132 + c4] = l2;
    }
    __syncthreads();

    // ---- P1: equivariant linear (hi/lo), norm/inner/muw epilogue
    {
        const int rt = wv >> 1, pp = wv & 1;
        const int node = rt * 4 + qd;
        bf16x8 ah[4], al[4];
        #pragma unroll
        for (int kt = 0; kt < 4; kt++) {
            ah[kt] = *(const bf16x8*)&AH_s[(rt * 16 + m) * 132 + qd * 8 + kt * 32];
            al[kt] = *(const bf16x8*)&AL_s[(rt * 16 + m) * 132 + qd * 8 + kt * 32];
        }
        __syncthreads();   // fragments in regs; planes switch to mlp1 layout

        // qn -> mlp1 planes cols [0,128) (same thread mapping as P0 staging)
        {
            int r = t >> 5, c4 = (t & 31) * 4;
            unsigned ph01, pl01, ph23, pl23;
            split_pair(qv.x, qv.y, ph01, pl01);
            split_pair(qv.z, qv.w, ph23, pl23);
            uint2 h2; h2.x = ph01; h2.y = ph23;
            uint2 l2; l2.x = pl01; l2.y = pl23;
            *(uint2*)&AH_s[r * 264 + c4] = h2;
            *(uint2*)&AL_s[r * 264 + c4] = l2;
        }

        #pragma unroll 1
        for (int jj = 0; jj < 4; jj++) {
            int ctv = 2 * jj + pp;
            f32x4 av = {0.f, 0.f, 0.f, 0.f};
            f32x4 aw = {0.f, 0.f, 0.f, 0.f};
            #pragma unroll
            for (int kt = 0; kt < 4; kt++) {
                size_t bov = ((size_t)(ctv * 4 + kt) * 64 + lane) * 8;
                size_t bow = ((size_t)((ctv + 8) * 4 + kt) * 64 + lane) * 8;
                bf16x8 bvh = *(const bf16x8*)(Bv_hi + bov);
                bf16x8 bvl = *(const bf16x8*)(Bv_lo + bov);
                bf16x8 bwh = *(const bf16x8*)(Bv_hi + bow);
                bf16x8 bwl = *(const bf16x8*)(Bv_lo + bow);
                av = __builtin_amdgcn_mfma_f32_16x16x32_bf16(al[kt], bvh, av, 0, 0, 0);
                av = __builtin_amdgcn_mfma_f32_16x16x32_bf16(ah[kt], bvl, av, 0, 0, 0);
                av = __builtin_amdgcn_mfma_f32_16x16x32_bf16(ah[kt], bvh, av, 0, 0, 0);
                aw = __builtin_amdgcn_mfma_f32_16x16x32_bf16(al[kt], bwh, aw, 0, 0, 0);
                aw = __builtin_amdgcn_mfma_f32_16x16x32_bf16(ah[kt], bwl, aw, 0, 0, 0);
                aw = __builtin_amdgcn_mfma_f32_16x16x32_bf16(ah[kt], bwh, aw, 0, 0, 0);
            }
            int cw = ctv * 16 + m;
            float v0 = av[0], v1 = av[1], v2 = av[2];
            float w0 = aw[0], w1 = aw[1], w2 = aw[2];
            float nv = sqrtf(v0 * v0 + v1 * v1 + v2 * v2 + 1e-8f);
            unsigned short nh = f2b(nv);
            AH_s[node * 264 + 128 + cw] = nh;
            AL_s[node * 264 + 128 + cw] = f2b(nv - b2f(nh));
            inner_s[node][cw] = v0 * w0 + v1 * w1 + v2 * w2;
            unsigned pw01 = cvtpk(w0, w1);
            muw_s[node * 3 + 0][cw] = (unsigned short)(pw01 & 0xFFFFu);
            muw_s[node * 3 + 1][cw] = (unsigned short)(pw01 >> 16);
            muw_s[node * 3 + 2][cw] = f2b(w2);
        }
    }
    __syncthreads();

    // ---- P2: mlp1 (A = [16][264] planes)
    f32x4 hacc[3] = {{0.f,0.f,0.f,0.f},{0.f,0.f,0.f,0.f},{0.f,0.f,0.f,0.f}};
    #pragma unroll 1
    for (int half = 0; half < 2; half++) {
        bf16x8 ah[4], al[4];
        #pragma unroll
        for (int u = 0; u < 4; u++) {
            ah[u] = *(const bf16x8*)&AH_s[m * 264 + half * 128 + qd * 8 + u * 32];
            al[u] = *(const bf16x8*)&AL_s[m * 264 + half * 128 + qd * 8 + u * 32];
        }
        #pragma unroll
        for (int jj = 0; jj < 3; jj++) {
            int ct = jj * 8 + wv;
            #pragma unroll
            for (int u = 0; u < 4; u++) {
                int kt = half * 4 + u;
                size_t bo = ((size_t)(ct * 8 + kt) * 64 + lane) * 8;
                bf16x8 bh = *(const bf16x8*)(B1_hi + bo);
                bf16x8 bl = *(const bf16x8*)(B1_lo + bo);
                hacc[jj] = __builtin_amdgcn_mfma_f32_16x16x32_bf16(al[u], bh, hacc[jj], 0, 0, 0);
                hacc[jj] = __builtin_amdgcn_mfma_f32_16x16x32_bf16(ah[u], bl, hacc[jj], 0, 0, 0);
                hacc[jj] = __builtin_amdgcn_mfma_f32_16x16x32_bf16(ah[u], bh, hacc[jj], 0, 0, 0);
            }
        }
    }
    __syncthreads();   // planes dead -> mlp2 layout

    // ---- P3: silu epilogue -> mlp2 planes [16][392] (cvt_pk pairs)
    #pragma unroll
    for (int jj = 0; jj < 3; jj++) {
        int ct = jj * 8 + wv;
        int c = ct * 16 + m;
        float bb = b_mix1[c];
        float s0 = silu_f(hacc[jj][0] + bb);
        float s1 = silu_f(hacc[jj][1] + bb);
        float s2 = silu_f(hacc[jj][2] + bb);
        float s3 = silu_f(hacc[jj][3] + bb);
        unsigned ph01, pl01, ph23, pl23;
        split_pair(s0, s1, ph01, pl01);
        split_pair(s2, s3, ph23, pl23);
        int nb = qd * 4;
        AH_s[(nb + 0) * 392 + c] = (unsigned short)(ph01 & 0xFFFFu);
        AH_s[(nb + 1) * 392 + c] = (unsigned short)(ph01 >> 16);
        AH_s[(nb + 2) * 392 + c] = (unsigned short)(ph23 & 0xFFFFu);
        AH_s[(nb + 3) * 392 + c] = (unsigned short)(ph23 >> 16);
        AL_s[(nb + 0) * 392 + c] = (unsigned short)(pl01 & 0xFFFFu);
        AL_s[(nb + 1) * 392 + c] = (unsigned short)(pl01 >> 16);
        AL_s[(nb + 2) * 392 + c] = (unsigned short)(pl23 & 0xFFFFu);
        AL_s[(nb + 3) * 392 + c] = (unsigned short)(pl23 >> 16);
    }
    __syncthreads();

    // ---- P4: mlp2 (A = [16][392] planes) + final epilogue
    {
        f32x4 dacc[3] = {{0.f,0.f,0.f,0.f},{0.f,0.f,0.f,0.f},{0.f,0.f,0.f,0.f}};
        #pragma unroll 1
        for (int half = 0; half < 2; half++) {
            bf16x8 ah[6], al[6];
            #pragma unroll
            for (int u = 0; u < 6; u++) {
                ah[u] = *(const bf16x8*)&AH_s[m * 392 + half * 192 + qd * 8 + u * 32];
                al[u] = *(const bf16x8*)&AL_s[m * 392 + half * 192 + qd * 8 + u * 32];
            }
            #pragma unroll
            for (int jj = 0; jj < 3; jj++) {
                int ct = jj * 8 + wv;
                #pragma unroll
                for (int u = 0; u < 6; u++) {
                    int kt = half * 6 + u;
                    size_t bo = ((size_t)(ct * 12 + kt) * 64 + lane) * 8;
                    bf16x8 bh = *(const bf16x8*)(B2_hi + bo);
                    bf16x8 bl = *(const bf16x8*)(B2_lo + bo);
                    dacc[jj] = __builtin_amdgcn_mfma_f32_16x16x32_bf16(al[u], bh, dacc[jj], 0, 0, 0);
                    dacc[jj] = __builtin_amdgcn_mfma_f32_16x16x32_bf16(ah[u], bl, dacc[jj], 0, 0, 0);
                    dacc[jj] = __builtin_amdgcn_mfma_f32_16x16x32_bf16(ah[u], bh, dacc[jj], 0, 0, 0);
                }
            }
        }
        const int c = wv * 16 + m;
        float bq = b_mix2[c], bs = b_mix2[128 + c], bu = b_mix2[256 + c];
        #pragma unroll
        for (int r = 0; r < 4; r++) {
            int node = qd * 4 + r;
            float dq   = dacc[0][r] + bq;
            float dms  = dacc[1][r] + bs;
            float dqmu = dacc[2][r] + bu;
            q_out[(size_t)(n0 + node) * H + c] =
                qn_s[node][c] + dq + dqmu * inner_s[node][c];
            #pragma unroll
            for (int d = 0; d < 3; d++) {
                size_t gi = ((size_t)(n0 + node) * 3 + d) * H + c;
                float mun = mu[gi] + acc_mu[(size_t)(n0 + node) * H3 + d * H + c];
                mu_out[gi] = mun + b2f(muw_s[node * 3 + d][c]) * dms;
            }
        }
    }
}

extern "C" void kernel_launch(void* const* d_in, const int* in_sizes, int n_in,
                              void* d_out, int out_size, void* d_ws, size_t ws_size,
                              hipStream_t stream) {
    const float* q        = (const float*)d_in[0];
    const float* mu       = (const float*)d_in[1];
    const int*   eidx     = (const int*)d_in[2];
    const float* rbf      = (const float*)d_in[3];
    const float* unitv    = (const float*)d_in[4];
    const float* cutoff   = (const float*)d_in[5];
    const float* W_inter1 = (const float*)d_in[6];
    const float* b_inter1 = (const float*)d_in[7];
    const float* W_inter2 = (const float*)d_in[8];
    const float* b_inter2 = (const float*)d_in[9];
    const float* W_filt1  = (const float*)d_in[10];
    const float* b_filt1  = (const float*)d_in[11];
    const float* W_filt2  = (const float*)d_in[12];
    const float* b_filt2  = (const float*)d_in[13];
    const float* W_vec    = (const float*)d_in[14];
    const float* W_mix1   = (const float*)d_in[15];
    const float* b_mix1   = (const float*)d_in[16];
    const float* W_mix2   = (const float*)d_in[17];
    const float* b_mix2   = (const float*)d_in[18];

    // workspace layout
    char* p = (char*)d_ws;
    float* acc_q       = (float*)p;            p += (size_t)NN * H * 4;
    float* acc_mu      = (float*)p;            p += (size_t)NN * H3 * 4;
    float* sorted_unit = (float*)p;            p += (size_t)NE * 3 * 4;
    int*   counts      = (int*)p;              p += (size_t)NN * 4;
    int*   off         = (int*)p;              p += (size_t)(NN + 1) * 4;
    p = (char*)(((size_t)p + 255) & ~(size_t)255);
    int*   cursor      = (int*)p;              p += (size_t)NN * 4;
    p = (char*)(((size_t)p + 255) & ~(size_t)255);
    int*   sorted_eid  = (int*)p;              p += (size_t)NE * 4;
    int*   sorted_src  = (int*)p;              p += (size_t)NE * 4;
    p = (char*)(((size_t)p + 255) & ~(size_t)255);
    unsigned short* Bp    = (unsigned short*)p; p += (size_t)H * H3 * 2;
    unsigned short* Bp1   = (unsigned short*)p; p += (size_t)H * H3 * 2;
    unsigned short* Bp2   = (unsigned short*)p; p += (size_t)H3 * H3 * 2;
    unsigned short* Bf1p  = (unsigned short*)p; p += (size_t)8 * 64 * 8 * 2;
    unsigned short* Bv_hi = (unsigned short*)p; p += (size_t)H * H2 * 2;
    unsigned short* Bv_lo = (unsigned short*)p; p += (size_t)H * H2 * 2;
    unsigned short* B1_hi = (unsigned short*)p; p += (size_t)H2 * H3 * 2;
    unsigned short* B1_lo = (unsigned short*)p; p += (size_t)H2 * H3 * 2;
    unsigned short* B2_hi = (unsigned short*)p; p += (size_t)H3 * H3 * 2;
    unsigned short* B2_lo = (unsigned short*)p; p += (size_t)H3 * H3 * 2;
    p = (char*)(((size_t)p + 255) & ~(size_t)255);
    unsigned short* x_b  = (unsigned short*)p;  p += (size_t)NN * H3 * 2;
    unsigned short* mu_b = (unsigned short*)p;  p += (size_t)NN * H3 * 2;
    p = (char*)(((size_t)p + 255) & ~(size_t)255);
    unsigned short* filt = (unsigned short*)p;  p += (size_t)NE * H3 * 2;

    float* q_out  = (float*)d_out;
    float* mu_out = q_out + (size_t)NN * H;

    hipMemsetAsync(counts, 0, (size_t)NN * 4, stream);

    hist_kernel    <<<NE / 256, 256, 0, stream>>>(eidx, counts);
    pack_all_kernel<<<1032, 64, 0, stream>>>(W_filt2, W_inter1, W_inter2, W_filt1,
                                             W_vec, W_mix1, W_mix2,
                                             Bp, Bp1, Bp2, Bf1p,
                                             Bv_hi, Bv_lo, B1_hi, B1_lo, B2_hi, B2_lo);
    scan_kernel    <<<1, 1024, 0, stream>>>(counts, off, cursor);
    place_kernel   <<<NE / 256, 256, 0, stream>>>(eidx, unitv, cursor,
                                                  sorted_eid, sorted_src, sorted_unit);
    node_x_kernel  <<<(NN + 31) / 32, 256, 0, stream>>>(q, Bp1, b_inter1, Bp2, b_inter2, x_b);
    mu2b_kernel    <<<NN * H3 / (4 * 256), 256, 0, stream>>>(mu, mu_b);
    filter_kernel  <<<NE / 64, 256, 0, stream>>>(rbf, cutoff, Bf1p, b_filt1,
                                                 Bp, b_filt2, filt);
    gather_kernel  <<<NN, 256, 0, stream>>>(off, sorted_eid, sorted_src, sorted_unit,
                                            filt, x_b, mu_b, acc_q, acc_mu);
    mix_kernel     <<<NN / 16, 512, 0, stream>>>(q, mu, acc_q, acc_mu,
                                                 Bv_hi, Bv_lo, B1_hi, B1_lo, B2_hi, B2_lo,
                                                 b_mix1, b_mix2, q_out, mu_out);
}

// Round 9
// 402.505 us; speedup vs baseline: 1.1171x; 1.0909x over previous
//
#include <hip/hip_runtime.h>

#define NN 10000
#define NE 256000
#define H 128
#define H2 256
#define H3 384
#define NRBF 20

typedef __attribute__((ext_vector_type(8))) short bf16x8;
typedef __attribute__((ext_vector_type(4))) float f32x4;

__device__ __forceinline__ float silu_f(float v) { return v / (1.f + __expf(-v)); }

// fp32 -> bf16 bits (RNE)
__device__ __forceinline__ unsigned short f2b(float f) {
    union { float f; unsigned u; } x; x.f = f;
    unsigned r = (x.u + 0x7FFFu + ((x.u >> 16) & 1u)) >> 16;
    return (unsigned short)r;
}
__device__ __forceinline__ float b2f(unsigned short b) {
    union { unsigned u; float f; } x; x.u = ((unsigned)b) << 16;
    return x.f;
}

// packed RNE f32x2 -> bf16x2 (1 VALU op; bit-identical to f2b pair)
__device__ __forceinline__ unsigned cvtpk(float lo, float hi) {
    unsigned r;
    asm("v_cvt_pk_bf16_f32 %0, %1, %2" : "=v"(r) : "v"(lo), "v"(hi));
    return r;
}
// hi/lo split of a value pair into packed hi-plane / lo-plane words
__device__ __forceinline__ void split_pair(float v0, float v1, unsigned &ph, unsigned &pl) {
    ph = cvtpk(v0, v1);
    union { unsigned u; float f; } a, b;
    a.u = ph << 16;            // bf16(v0) as f32 bits
    b.u = ph & 0xFFFF0000u;    // bf16(v1) as f32 bits
    pl = cvtpk(v0 - a.f, v1 - b.f);
}

// ---------------------------------------------------------------------------
// CSR build (hist + scan stay standalone; place is folded into mega)
// ---------------------------------------------------------------------------
__global__ __launch_bounds__(256) void hist_kernel(const int* __restrict__ eidx,
                                                   int* __restrict__ counts) {
    int e = blockIdx.x * 256 + threadIdx.x;
    atomicAdd(&counts[eidx[e]], 1);
}

__global__ __launch_bounds__(1024) void scan_kernel(const int* __restrict__ counts,
                                                    int* __restrict__ off,
                                                    int* __restrict__ cursor) {
    __shared__ int sums[1024];
    const int t = threadIdx.x;
    const int base = t * 10;
    int local[10];
    int s = 0;
    #pragma unroll
    for (int i = 0; i < 10; i++) {
        int idx = base + i;
        int v = (idx < NN) ? counts[idx] : 0;
        local[i] = s; s += v;
    }
    sums[t] = s;
    __syncthreads();
    for (int d = 1; d < 1024; d <<= 1) {
        int v = (t >= d) ? sums[t - d] : 0;
        __syncthreads();
        sums[t] += v;
        __syncthreads();
    }
    int prefix = (t > 0) ? sums[t - 1] : 0;
    #pragma unroll
    for (int i = 0; i < 10; i++) {
        int idx = base + i;
        if (idx < NN) { off[idx] = prefix + local[i]; cursor[idx] = prefix + local[i]; }
    }
    if (t == 1023) off[NN] = sums[1023];
}

// ---------------------------------------------------------------------------
// Unified weight packing (one launch). 64-thread blocks, range-switched.
// ---------------------------------------------------------------------------
__device__ __forceinline__ void pack_hi_one(const float* __restrict__ W, int K, int N,
                                            unsigned short* __restrict__ dst,
                                            int b, int lane) {
    const int KT = K >> 5;
    const int kt = b % KT, ct = b / KT;
    const int m = lane & 15, qd = lane >> 4;
    size_t base = ((size_t)(ct * KT + kt) * 64 + lane) * 8;
    unsigned short v[8];
    #pragma unroll
    for (int j = 0; j < 8; j++) {
        int k = kt * 32 + qd * 8 + j;
        v[j] = f2b(W[(size_t)k * N + ct * 16 + m]);
    }
    *(ushort4*)&dst[base]     = *(ushort4*)&v[0];
    *(ushort4*)&dst[base + 4] = *(ushort4*)&v[4];
}

__device__ __forceinline__ void pack_split_one(const float* __restrict__ W, int K, int N,
                                               unsigned short* __restrict__ hi,
                                               unsigned short* __restrict__ lo,
                                               int b, int lane) {
    const int KT = K >> 5;
    const int kt = b % KT, ct = b / KT;
    const int m = lane & 15, qd = lane >> 4;
    size_t base = ((size_t)(ct * KT + kt) * 64 + lane) * 8;
    #pragma unroll
    for (int j = 0; j < 8; j++) {
        int k = kt * 32 + qd * 8 + j;
        float v = W[(size_t)k * N + ct * 16 + m];
        unsigned short h = f2b(v);
        hi[base + j] = h;
        lo[base + j] = f2b(v - b2f(h));
    }
}

__global__ __launch_bounds__(64) void pack_all_kernel(
    const float* __restrict__ Wf2, const float* __restrict__ Wi1,
    const float* __restrict__ Wi2, const float* __restrict__ Wf1,
    const float* __restrict__ Wv, const float* __restrict__ Wm1,
    const float* __restrict__ Wm2,
    unsigned short* __restrict__ Bp, unsigned short* __restrict__ Bp1,
    unsigned short* __restrict__ Bp2, unsigned short* __restrict__ Bf1p,
    unsigned short* __restrict__ Bv_hi, unsigned short* __restrict__ Bv_lo,
    unsigned short* __restrict__ B1_hi, unsigned short* __restrict__ B1_lo,
    unsigned short* __restrict__ B2_hi, unsigned short* __restrict__ B2_lo) {
    const int b = blockIdx.x;
    const int lane = threadIdx.x;
    if (b < 96)        pack_hi_one(Wf2, H, H3, Bp, b, lane);
    else if (b < 192)  pack_hi_one(Wi1, H, H3, Bp1, b - 96, lane);
    else if (b < 480)  pack_hi_one(Wi2, H3, H3, Bp2, b - 192, lane);
    else if (b < 488) {                               // Wf1: K=20 zero-padded to 32
        const int ct = b - 480;
        const int m = lane & 15, qd = lane >> 4;
        size_t base = ((size_t)ct * 64 + lane) * 8;
        unsigned short v[8];
        #pragma unroll
        for (int j = 0; j < 8; j++) {
            int k = qd * 8 + j;
            v[j] = (k < NRBF) ? f2b(Wf1[(size_t)k * H + ct * 16 + m]) : (unsigned short)0;
        }
        *(ushort4*)&Bf1p[base]     = *(ushort4*)&v[0];
        *(ushort4*)&Bf1p[base + 4] = *(ushort4*)&v[4];
    }
    else if (b < 552)  pack_split_one(Wv,  H,  H2, Bv_hi, Bv_lo, b - 488, lane);
    else if (b < 744)  pack_split_one(Wm1, H2, H3, B1_hi, B1_lo, b - 552, lane);
    else if (b < 1032) pack_split_one(Wm2, H3, H3, B2_hi, B2_lo, b - 744, lane);
}

// ---------------------------------------------------------------------------
// MEGA kernel bodies (device functions sharing one 50.4KB LDS union).
// R8: place / node_x / mu2b / filter are mutually independent (all depend
// only on scan+pack_all). Serial launches left node_x (313 blocks, 1.2/CU)
// fully latency-exposed. Grid-concatenated: node_x blocks FIRST (thin,
// long-latency), then place, mu2b; filter's 4000 blocks backfill all
// remaining slots -> co-residency fills idle issue ports.
// ---------------------------------------------------------------------------

__device__ void node_x_body(int bid, char* smem,
    const float* __restrict__ q,
    const unsigned short* __restrict__ Bp1, const float* __restrict__ b1,
    const unsigned short* __restrict__ Bp2, const float* __restrict__ b2,
    unsigned short* __restrict__ x_b) {
    unsigned short* qa_s = (unsigned short*)smem;           // 32*136 u16 = 8704 B
    unsigned short* h1_s = (unsigned short*)(smem + 8704);  // 32*392 u16 = 25088 B
    const int t = threadIdx.x;
    const int wv = t >> 6, lane = t & 63;
    const int m = lane & 15, qd = lane >> 4;
    const int st = wv >> 1, ch = wv & 1;
    const int n0 = bid * 32;

    for (int i = t; i < 32 * 32; i += 256) {
        int r = i >> 5, c4 = (i & 31) * 4;
        int node = n0 + r;
        uint2 o;
        if (node < NN) {
            float4 v = *(const float4*)&q[(size_t)node * H + c4];
            o.x = cvtpk(v.x, v.y);
            o.y = cvtpk(v.z, v.w);
        } else { o.x = o.y = 0; }
        *(uint2*)&qa_s[r * 136 + c4] = o;
    }
    __syncthreads();

    {
        const unsigned short* arow = &qa_s[(st * 16 + m) * 136 + qd * 8];
        #pragma unroll 1
        for (int jc = 0; jc < 12; jc++) {
            int ct = ch * 12 + jc;
            f32x4 acc = {0.f, 0.f, 0.f, 0.f};
            #pragma unroll
            for (int kt = 0; kt < 4; kt++) {
                bf16x8 af = *(const bf16x8*)(arow + kt * 32);
                bf16x8 bfr = *(const bf16x8*)(Bp1 + ((size_t)(ct * 4 + kt) * 64 + lane) * 8);
                acc = __builtin_amdgcn_mfma_f32_16x16x32_bf16(af, bfr, acc, 0, 0, 0);
            }
            int col = ct * 16 + m;
            float bb = b1[col];
            unsigned p01 = cvtpk(silu_f(acc[0] + bb), silu_f(acc[1] + bb));
            unsigned p23 = cvtpk(silu_f(acc[2] + bb), silu_f(acc[3] + bb));
            int rb = st * 16 + qd * 4;
            h1_s[(rb + 0) * 392 + col] = (unsigned short)(p01 & 0xFFFFu);
            h1_s[(rb + 1) * 392 + col] = (unsigned short)(p01 >> 16);
            h1_s[(rb + 2) * 392 + col] = (unsigned short)(p23 & 0xFFFFu);
            h1_s[(rb + 3) * 392 + col] = (unsigned short)(p23 >> 16);
        }
    }
    __syncthreads();

    {
        const unsigned short* arow = &h1_s[(st * 16 + m) * 392 + qd * 8];
        #pragma unroll 1
        for (int jc = 0; jc < 12; jc++) {
            int ct = ch * 12 + jc;
            f32x4 acc = {0.f, 0.f, 0.f, 0.f};
            #pragma unroll
            for (int kt = 0; kt < 12; kt++) {
                bf16x8 af = *(const bf16x8*)(arow + kt * 32);
                bf16x8 bfr = *(const bf16x8*)(Bp2 + ((size_t)(ct * 12 + kt) * 64 + lane) * 8);
                acc = __builtin_amdgcn_mfma_f32_16x16x32_bf16(af, bfr, acc, 0, 0, 0);
            }
            int col = ct * 16 + m;
            float bb = b2[col];
            unsigned p01 = cvtpk(acc[0] + bb, acc[1] + bb);
            unsigned p23 = cvtpk(acc[2] + bb, acc[3] + bb);
            int rb = n0 + st * 16 + qd * 4;
            if (rb + 0 < NN) x_b[(size_t)(rb + 0) * H3 + col] = (unsigned short)(p01 & 0xFFFFu);
            if (rb + 1 < NN) x_b[(size_t)(rb + 1) * H3 + col] = (unsigned short)(p01 >> 16);
            if (rb + 2 < NN) x_b[(size_t)(rb + 2) * H3 + col] = (unsigned short)(p23 & 0xFFFFu);
            if (rb + 3 < NN) x_b[(size_t)(rb + 3) * H3 + col] = (unsigned short)(p23 >> 16);
        }
    }
}

__device__ void place_body(int bid,
    const int* __restrict__ eidx, const float* __restrict__ unitv,
    int* __restrict__ cursor, int* __restrict__ sorted_eid,
    int* __restrict__ sorted_src, float* __restrict__ sorted_unit) {
    int e = bid * 256 + threadIdx.x;
    int tgt = eidx[e];
    int src = eidx[NE + e];
    int pos = atomicAdd(&cursor[tgt], 1);
    sorted_eid[pos] = e;
    sorted_src[pos] = src;
    sorted_unit[pos * 3 + 0] = unitv[(size_t)e * 3 + 0];
    sorted_unit[pos * 3 + 1] = unitv[(size_t)e * 3 + 1];
    sorted_unit[pos * 3 + 2] = unitv[(size_t)e * 3 + 2];
}

__device__ void mu2b_body(int bid, const float* __restrict__ mu,
                          unsigned short* __restrict__ mu_b) {
    int i = bid * 256 + threadIdx.x;
    float4 v = ((const float4*)mu)[i];
    uint2 o;
    o.x = cvtpk(v.x, v.y);
    o.y = cvtpk(v.z, v.w);
    ((uint2*)mu_b)[i] = o;
}

__device__ void filter_body(int bid, char* smem,
    const float* __restrict__ rbf, const float* __restrict__ cutoff,
    const unsigned short* __restrict__ Bf1p, const float* __restrict__ bf1,
    const unsigned short* __restrict__ Bp, const float* __restrict__ bf2,
    unsigned short* __restrict__ filt) {
    float (*rbf_s)[21] = (float (*)[21])smem;                             // L1 input
    unsigned short (*h1_s)[136] = (unsigned short (*)[136])(smem + 5376); // L1 output
    unsigned short (*out_s)[392] = (unsigned short (*)[392])smem;         // L2 output
    float* cut_s = (float*)(smem + 50176);                                // 256 B

    const int t = threadIdx.x;
    const int wv = t >> 6, lane = t & 63;
    const int m = lane & 15, qd = lane >> 4;
    const size_t e0 = (size_t)bid * 64;

    if (t < 64) cut_s[t] = cutoff[e0 + t];
    for (int i = t; i < 64 * NRBF; i += 256) {          // coalesced
        rbf_s[i / NRBF][i % NRBF] = rbf[e0 * NRBF + i];
    }
    __syncthreads();

    // layer 1 MFMA: wave wv owns slot-tile wv (rows wv*16..wv*16+15)
    {
        bf16x8 af;
        {
            union { unsigned u[4]; bf16x8 v; } cu;
            #pragma unroll
            for (int i = 0; i < 4; i++) {
                int k0 = qd * 8 + 2 * i;
                float v0 = (k0 < NRBF) ? rbf_s[wv * 16 + m][k0] : 0.f;
                float v1 = (k0 + 1 < NRBF) ? rbf_s[wv * 16 + m][k0 + 1] : 0.f;
                cu.u[i] = cvtpk(v0, v1);
            }
            af = cu.v;
        }
        #pragma unroll
        for (int ct = 0; ct < 8; ct++) {
            f32x4 acc = {0.f, 0.f, 0.f, 0.f};
            bf16x8 bfr = *(const bf16x8*)(Bf1p + ((size_t)ct * 64 + lane) * 8);
            acc = __builtin_amdgcn_mfma_f32_16x16x32_bf16(af, bfr, acc, 0, 0, 0);
            int col = ct * 16 + m;
            float bb = bf1[col];
            unsigned p01 = cvtpk(silu_f(acc[0] + bb), silu_f(acc[1] + bb));
            unsigned p23 = cvtpk(silu_f(acc[2] + bb), silu_f(acc[3] + bb));
            int rb = wv * 16 + qd * 4;
            h1_s[rb + 0][col] = (unsigned short)(p01 & 0xFFFFu);
            h1_s[rb + 1][col] = (unsigned short)(p01 >> 16);
            h1_s[rb + 2][col] = (unsigned short)(p23 & 0xFFFFu);
            h1_s[rb + 3][col] = (unsigned short)(p23 >> 16);
        }
    }
    __syncthreads();

    // layer 2: wave wv -> cols [wv*96, wv*96+96), all 64 edge rows.
    {
        bf16x8 hfr[4][4];
        #pragma unroll
        for (int et = 0; et < 4; et++) {
            #pragma unroll
            for (int kt = 0; kt < 4; kt++) {
                hfr[et][kt] = *(const bf16x8*)&h1_s[et * 16 + m][qd * 8 + kt * 32];
            }
        }
        float cutv[4];
        #pragma unroll
        for (int et = 0; et < 4; et++) cutv[et] = cut_s[et * 16 + m];
        __syncthreads();   // all waves done reading h1_s -> smem becomes out_s

        #pragma unroll
        for (int cc = 0; cc < 6; cc++) {
            const int ct = wv * 6 + cc;
            bf16x8 w0 = *(const bf16x8*)(Bp + ((size_t)(ct * 4 + 0) * 64 + lane) * 8);
            bf16x8 w1 = *(const bf16x8*)(Bp + ((size_t)(ct * 4 + 1) * 64 + lane) * 8);
            bf16x8 w2 = *(const bf16x8*)(Bp + ((size_t)(ct * 4 + 2) * 64 + lane) * 8);
            bf16x8 w3 = *(const bf16x8*)(Bp + ((size_t)(ct * 4 + 3) * 64 + lane) * 8);
            f32x4 acc0 = {0.f, 0.f, 0.f, 0.f};
            f32x4 acc1 = {0.f, 0.f, 0.f, 0.f};
            f32x4 acc2 = {0.f, 0.f, 0.f, 0.f};
            f32x4 acc3 = {0.f, 0.f, 0.f, 0.f};
            acc0 = __builtin_amdgcn_mfma_f32_16x16x32_bf16(w0, hfr[0][0], acc0, 0, 0, 0);
            acc1 = __builtin_amdgcn_mfma_f32_16x16x32_bf16(w0, hfr[1][0], acc1, 0, 0, 0);
            acc2 = __builtin_amdgcn_mfma_f32_16x16x32_bf16(w0, hfr[2][0], acc2, 0, 0, 0);
            acc3 = __builtin_amdgcn_mfma_f32_16x16x32_bf16(w0, hfr[3][0], acc3, 0, 0, 0);
            acc0 = __builtin_amdgcn_mfma_f32_16x16x32_bf16(w1, hfr[0][1], acc0, 0, 0, 0);
            acc1 = __builtin_amdgcn_mfma_f32_16x16x32_bf16(w1, hfr[1][1], acc1, 0, 0, 0);
            acc2 = __builtin_amdgcn_mfma_f32_16x16x32_bf16(w1, hfr[2][1], acc2, 0, 0, 0);
            acc3 = __builtin_amdgcn_mfma_f32_16x16x32_bf16(w1, hfr[3][1], acc3, 0, 0, 0);
            acc0 = __builtin_amdgcn_mfma_f32_16x16x32_bf16(w2, hfr[0][2], acc0, 0, 0, 0);
            acc1 = __builtin_amdgcn_mfma_f32_16x16x32_bf16(w2, hfr[1][2], acc1, 0, 0, 0);
            acc2 = __builtin_amdgcn_mfma_f32_16x16x32_bf16(w2, hfr[2][2], acc2, 0, 0, 0);
            acc3 = __builtin_amdgcn_mfma_f32_16x16x32_bf16(w2, hfr[3][2], acc3, 0, 0, 0);
            acc0 = __builtin_amdgcn_mfma_f32_16x16x32_bf16(w3, hfr[0][3], acc0, 0, 0, 0);
            acc1 = __builtin_amdgcn_mfma_f32_16x16x32_bf16(w3, hfr[1][3], acc1, 0, 0, 0);
            acc2 = __builtin_amdgcn_mfma_f32_16x16x32_bf16(w3, hfr[2][3], acc2, 0, 0, 0);
            acc3 = __builtin_amdgcn_mfma_f32_16x16x32_bf16(w3, hfr[3][3], acc3, 0, 0, 0);

            float4 bb = *(const float4*)&bf2[ct * 16 + qd * 4];
            const int colb = ct * 16 + qd * 4;
            #pragma unroll
            for (int et = 0; et < 4; et++) {
                f32x4 a = (et == 0) ? acc0 : (et == 1) ? acc1 : (et == 2) ? acc2 : acc3;
                float c = cutv[et];
                float o0 = (a[0] + bb.x) * c;
                float o1 = (a[1] + bb.y) * c;
                float o2 = (a[2] + bb.z) * c;
                float o3 = (a[3] + bb.w) * c;
                uint2 st; st.x = cvtpk(o0, o1); st.y = cvtpk(o2, o3);
                *(uint2*)&out_s[et * 16 + m][colb] = st;
            }
        }
    }
    __syncthreads();

    // streaming writeout: 64 rows x 768 B contiguous (48 KB block region)
    #pragma unroll
    for (int i = 0; i < 12; i++) {
        int u = i * 256 + t;
        int row = u / 48, c16 = u % 48;
        *(uint4*)&filt[(e0 + row) * H3 + c16 * 8] = *(const uint4*)&out_s[row][c16 * 8];
    }
}

#define NX_BLOCKS 313
#define PL_BLOCKS 1000
#define MB_BLOCKS 3750
#define FL_BLOCKS 4000

__global__ __launch_bounds__(256) void mega_kernel(
    const float* __restrict__ q,
    const unsigned short* __restrict__ Bp1, const float* __restrict__ b1,
    const unsigned short* __restrict__ Bp2, const float* __restrict__ b2,
    unsigned short* __restrict__ x_b,
    const int* __restrict__ eidx, const float* __restrict__ unitv,
    int* __restrict__ cursor, int* __restrict__ sorted_eid,
    int* __restrict__ sorted_src, float* __restrict__ sorted_unit,
    const float* __restrict__ mu, unsigned short* __restrict__ mu_b,
    const float* __restrict__ rbf, const float* __restrict__ cutoff,
    const unsigned short* __restrict__ Bf1p, const float* __restrict__ bf1,
    const unsigned short* __restrict__ Bp, const float* __restrict__ bf2,
    unsigned short* __restrict__ filt) {
    __shared__ __align__(16) char smem[50432];
    int bid = blockIdx.x;
    if (bid < NX_BLOCKS) {
        node_x_body(bid, smem, q, Bp1, b1, Bp2, b2, x_b);
        return;
    }
    bid -= NX_BLOCKS;
    if (bid < PL_BLOCKS) {
        place_body(bid, eidx, unitv, cursor, sorted_eid, sorted_src, sorted_unit);
        return;
    }
    bid -= PL_BLOCKS;
    if (bid < MB_BLOCKS) {
        mu2b_body(bid, mu, mu_b);
        return;
    }
    bid -= MB_BLOCKS;
    filter_body(bid, smem, rbf, cutoff, Bf1p, bf1, Bp, bf2, filt);
}

// ---------------------------------------------------------------------------
// Gather: filt indexed through sorted_eid (filter runs in original order).
// ---------------------------------------------------------------------------
__global__ __launch_bounds__(256) void gather_kernel(
    const int* __restrict__ off, const int* __restrict__ sorted_eid,
    const int* __restrict__ sorted_src, const float* __restrict__ sorted_unit,
    const unsigned short* __restrict__ filt,
    const unsigned short* __restrict__ x_b, const unsigned short* __restrict__ mu_b,
    float* __restrict__ acc_q, float* __restrict__ acc_mu) {
    __shared__ float red_s[16][128];
    const int t = threadIdx.x;
    const int n = blockIdx.x;
    const int g = t >> 6, lane = t & 63;
    const int c2 = lane * 2;
    const int j0 = off[n], j1 = off[n + 1];

    float aq0 = 0.f, aq1 = 0.f, a00 = 0.f, a01 = 0.f;
    float a10 = 0.f, a11 = 0.f, a20 = 0.f, a21 = 0.f;
    for (int j = j0 + g; j < j1; j += 4) {
        int e = sorted_eid[j];
        int src = sorted_src[j];
        float u0 = sorted_unit[j * 3 + 0];
        float u1 = sorted_unit[j * 3 + 1];
        float u2 = sorted_unit[j * 3 + 2];
        const unsigned short* frow = filt + (size_t)e * H3 + c2;
        const unsigned short* xrow = x_b + (size_t)src * H3 + c2;
        const unsigned short* murow = mu_b + (size_t)src * H3 + c2;
        ushort2 fq = *(const ushort2*)(frow);
        ushort2 fr = *(const ushort2*)(frow + H);
        ushort2 fm = *(const ushort2*)(frow + 2 * H);
        ushort2 xq = *(const ushort2*)(xrow);
        ushort2 xr = *(const ushort2*)(xrow + H);
        ushort2 xm = *(const ushort2*)(xrow + 2 * H);
        ushort2 m0 = *(const ushort2*)(murow);
        ushort2 m1 = *(const ushort2*)(murow + H);
        ushort2 m2 = *(const ushort2*)(murow + 2 * H);
        float xrs0 = b2f(xr.x) * b2f(fr.x), xrs1 = b2f(xr.y) * b2f(fr.y);
        float xms0 = b2f(xm.x) * b2f(fm.x), xms1 = b2f(xm.y) * b2f(fm.y);
        aq0 = fmaf(b2f(xq.x), b2f(fq.x), aq0);
        aq1 = fmaf(b2f(xq.y), b2f(fq.y), aq1);
        a00 = fmaf(u0, xrs0, a00); a00 = fmaf(b2f(m0.x), xms0, a00);
        a01 = fmaf(u0, xrs1, a01); a01 = fmaf(b2f(m0.y), xms1, a01);
        a10 = fmaf(u1, xrs0, a10); a10 = fmaf(b2f(m1.x), xms0, a10);
        a11 = fmaf(u1, xrs1, a11); a11 = fmaf(b2f(m1.y), xms1, a11);
        a20 = fmaf(u2, xrs0, a20); a20 = fmaf(b2f(m2.x), xms0, a20);
        a21 = fmaf(u2, xrs1, a21); a21 = fmaf(b2f(m2.y), xms1, a21);
    }
    red_s[g * 4 + 0][c2] = aq0; red_s[g * 4 + 0][c2 + 1] = aq1;
    red_s[g * 4 + 1][c2] = a00; red_s[g * 4 + 1][c2 + 1] = a01;
    red_s[g * 4 + 2][c2] = a10; red_s[g * 4 + 2][c2 + 1] = a11;
    red_s[g * 4 + 3][c2] = a20; red_s[g * 4 + 3][c2 + 1] = a21;
    __syncthreads();
    if (t < 128) {
        float vq = red_s[0][t] + red_s[4][t] + red_s[8][t] + red_s[12][t];
        float v0 = red_s[1][t] + red_s[5][t] + red_s[9][t] + red_s[13][t];
        float v1 = red_s[2][t] + red_s[6][t] + red_s[10][t] + red_s[14][t];
        float v2 = red_s[3][t] + red_s[7][t] + red_s[11][t] + red_s[15][t];
        acc_q[(size_t)n * H + t] = vq;
        acc_mu[(size_t)n * H3 + t] = v0;
        acc_mu[(size_t)n * H3 + H + t] = v1;
        acc_mu[(size_t)n * H3 + 2 * H + t] = v2;
    }
}

// ---------------------------------------------------------------------------
// Mixing v5 (unchanged from R7): producer-side hi/lo planes + packed staging.
// ---------------------------------------------------------------------------
__global__ __launch_bounds__(512, 4) void mix_kernel(
    const float* __restrict__ q, const float* __restrict__ mu,
    const float* __restrict__ acc_q, const float* __restrict__ acc_mu,
    const unsigned short* __restrict__ Bv_hi, const unsigned short* __restrict__ Bv_lo,
    const unsigned short* __restrict__ B1_hi, const unsigned short* __restrict__ B1_lo,
    const unsigned short* __restrict__ B2_hi, const unsigned short* __restrict__ B2_lo,
    const float* __restrict__ b_mix1, const float* __restrict__ b_mix2,
    float* __restrict__ q_out, float* __restrict__ mu_out) {

    __shared__ __align__(16) unsigned short AH_s[64 * 132];
    __shared__ __align__(16) unsigned short AL_s[64 * 132];
    __shared__ __align__(16) float qn_s[16][128];
    __shared__ __align__(16) float inner_s[16][128];
    __shared__ __align__(16) unsigned short muw_s[48][136];

    const int t = threadIdx.x;
    const int wv = t >> 6, lane = t & 63;
    const int m = lane & 15, qd = lane >> 4;
    const int n0 = blockIdx.x * 16;

    // ---- P0: stage qn (f32 + regs) and equivariant A as hi/lo planes
    float4 qv;
    {
        int r = t >> 5, c4 = (t & 31) * 4;
        float4 a = *(const float4*)&q[(size_t)(n0 + r) * H + c4];
        float4 b = *(const float4*)&acc_q[(size_t)(n0 + r) * H + c4];
        qv.x = a.x + b.x; qv.y = a.y + b.y; qv.z = a.z + b.z; qv.w = a.w + b.w;
        *(float4*)&qn_s[r][c4] = qv;
    }
    for (int i = t; i < 64 * 32; i += 512) {
        int r = i >> 5, c4 = (i & 31) * 4;
        int n = r >> 2, d = r & 3;
        float v[4];
        if (d < 3) {
            float4 a = *(const float4*)&mu[((size_t)(n0 + n) * 3 + d) * H + c4];
            float4 b = *(const float4*)&acc_mu[(size_t)(n0 + n) * H3 + d * H + c4];
            v[0] = a.x + b.x; v[1] = a.y + b.y; v[2] = a.z + b.z; v[3] = a.w + b.w;
        } else { v[0] = v[1] = v[2] = v[3] = 0.f; }
        unsigned ph01, pl01, ph23, pl23;
        split_pair(v[0], v[1], ph01, pl01);
        split_pair(v[2], v[3], ph23, pl23);
        uint2 h2; h2.x = ph01; h2.y = ph23;
        uint2 l2; l2.x = pl01; l2.y = pl23;
        *(uint2*)&AH_s[r * 132 + c4] = h2;
        *(uint2*)&AL_s[r * 132 + c4] = l2;
    }
    __syncthreads();

    // ---- P1: equivariant linear (hi/lo), norm/inner/muw epilogue
    {
        const int rt = wv >> 1, pp = wv & 1;
        const int node = rt * 4 + qd;
        bf16x8 ah[4], al[4];
        #pragma unroll
        for (int kt = 0; kt < 4; kt++) {
            ah[kt] = *(const bf16x8*)&AH_s[(rt * 16 + m) * 132 + qd * 8 + kt * 32];
            al[kt] = *(const bf16x8*)&AL_s[(rt * 16 + m) * 132 + qd * 8 + kt * 32];
        }
        __syncthreads();   // fragments in regs; planes switch to mlp1 layout

        // qn -> mlp1 planes cols [0,128) (same thread mapping as P0 staging)
        {
            int r = t >> 5, c4 = (t & 31) * 4;
            unsigned ph01, pl01, ph23, pl23;
            split_pair(qv.x, qv.y, ph01, pl01);
            split_pair(qv.z, qv.w, ph23, pl23);
            uint2 h2; h2.x = ph01; h2.y = ph23;
            uint2 l2; l2.x = pl01; l2.y = pl23;
            *(uint2*)&AH_s[r * 264 + c4] = h2;
            *(uint2*)&AL_s[r * 264 + c4] = l2;
        }

        #pragma unroll 1
        for (int jj = 0; jj < 4; jj++) {
            int ctv = 2 * jj + pp;
            f32x4 av = {0.f, 0.f, 0.f, 0.f};
            f32x4 aw = {0.f, 0.f, 0.f, 0.f};
            #pragma unroll
            for (int kt = 0; kt < 4; kt++) {
                size_t bov = ((size_t)(ctv * 4 + kt) * 64 + lane) * 8;
                size_t bow = ((size_t)((ctv + 8) * 4 + kt) * 64 + lane) * 8;
                bf16x8 bvh = *(const bf16x8*)(Bv_hi + bov);
                bf16x8 bvl = *(const bf16x8*)(Bv_lo + bov);
                bf16x8 bwh = *(const bf16x8*)(Bv_hi + bow);
                bf16x8 bwl = *(const bf16x8*)(Bv_lo + bow);
                av = __builtin_amdgcn_mfma_f32_16x16x32_bf16(al[kt], bvh, av, 0, 0, 0);
                av = __builtin_amdgcn_mfma_f32_16x16x32_bf16(ah[kt], bvl, av, 0, 0, 0);
                av = __builtin_amdgcn_mfma_f32_16x16x32_bf16(ah[kt], bvh, av, 0, 0, 0);
                aw = __builtin_amdgcn_mfma_f32_16x16x32_bf16(al[kt], bwh, aw, 0, 0, 0);
                aw = __builtin_amdgcn_mfma_f32_16x16x32_bf16(ah[kt], bwl, aw, 0, 0, 0);
                aw = __builtin_amdgcn_mfma_f32_16x16x32_bf16(ah[kt], bwh, aw, 0, 0, 0);
            }
            int cw = ctv * 16 + m;
            float v0 = av[0], v1 = av[1], v2 = av[2];
            float w0 = aw[0], w1 = aw[1], w2 = aw[2];
            float nv = sqrtf(v0 * v0 + v1 * v1 + v2 * v2 + 1e-8f);
            unsigned short nh = f2b(nv);
            AH_s[node * 264 + 128 + cw] = nh;
            AL_s[node * 264 + 128 + cw] = f2b(nv - b2f(nh));
            inner_s[node][cw] = v0 * w0 + v1 * w1 + v2 * w2;
            unsigned pw01 = cvtpk(w0, w1);
            muw_s[node * 3 + 0][cw] = (unsigned short)(pw01 & 0xFFFFu);
            muw_s[node * 3 + 1][cw] = (unsigned short)(pw01 >> 16);
            muw_s[node * 3 + 2][cw] = f2b(w2);
        }
    }
    __syncthreads();

    // ---- P2: mlp1 (A = [16][264] planes)
    f32x4 hacc[3] = {{0.f,0.f,0.f,0.f},{0.f,0.f,0.f,0.f},{0.f,0.f,0.f,0.f}};
    #pragma unroll 1
    for (int half = 0; half < 2; half++) {
        bf16x8 ah[4], al[4];
        #pragma unroll
        for (int u = 0; u < 4; u++) {
            ah[u] = *(const bf16x8*)&AH_s[m * 264 + half * 128 + qd * 8 + u * 32];
            al[u] = *(const bf16x8*)&AL_s[m * 264 + half * 128 + qd * 8 + u * 32];
        }
        #pragma unroll
        for (int jj = 0; jj < 3; jj++) {
            int ct = jj * 8 + wv;
            #pragma unroll
            for (int u = 0; u < 4; u++) {
                int kt = half * 4 + u;
                size_t bo = ((size_t)(ct * 8 + kt) * 64 + lane) * 8;
                bf16x8 bh = *(const bf16x8*)(B1_hi + bo);
                bf16x8 bl = *(const bf16x8*)(B1_lo + bo);
                hacc[jj] = __builtin_amdgcn_mfma_f32_16x16x32_bf16(al[u], bh, hacc[jj], 0, 0, 0);
                hacc[jj] = __builtin_amdgcn_mfma_f32_16x16x32_bf16(ah[u], bl, hacc[jj], 0, 0, 0);
                hacc[jj] = __builtin_amdgcn_mfma_f32_16x16x32_bf16(ah[u], bh, hacc[jj], 0, 0, 0);
            }
        }
    }
    __syncthreads();   // planes dead -> mlp2 layout

    // ---- P3: silu epilogue -> mlp2 planes [16][392] (cvt_pk pairs)
    #pragma unroll
    for (int jj = 0; jj < 3; jj++) {
        int ct = jj * 8 + wv;
        int c = ct * 16 + m;
        float bb = b_mix1[c];
        float s0 = silu_f(hacc[jj][0] + bb);
        float s1 = silu_f(hacc[jj][1] + bb);
        float s2 = silu_f(hacc[jj][2] + bb);
        float s3 = silu_f(hacc[jj][3] + bb);
        unsigned ph01, pl01, ph23, pl23;
        split_pair(s0, s1, ph01, pl01);
        split_pair(s2, s3, ph23, pl23);
        int nb = qd * 4;
        AH_s[(nb + 0) * 392 + c] = (unsigned short)(ph01 & 0xFFFFu);
        AH_s[(nb + 1) * 392 + c] = (unsigned short)(ph01 >> 16);
        AH_s[(nb + 2) * 392 + c] = (unsigned short)(ph23 & 0xFFFFu);
        AH_s[(nb + 3) * 392 + c] = (unsigned short)(ph23 >> 16);
        AL_s[(nb + 0) * 392 + c] = (unsigned short)(pl01 & 0xFFFFu);
        AL_s[(nb + 1) * 392 + c] = (unsigned short)(pl01 >> 16);
        AL_s[(nb + 2) * 392 + c] = (unsigned short)(pl23 & 0xFFFFu);
        AL_s[(nb + 3) * 392 + c] = (unsigned short)(pl23 >> 16);
    }
    __syncthreads();

    // ---- P4: mlp2 (A = [16][392] planes) + final epilogue
    {
        f32x4 dacc[3] = {{0.f,0.f,0.f,0.f},{0.f,0.f,0.f,0.f},{0.f,0.f,0.f,0.f}};
        #pragma unroll 1
        for (int half = 0; half < 2; half++) {
            bf16x8 ah[6], al[6];
            #pragma unroll
            for (int u = 0; u < 6; u++) {
                ah[u] = *(const bf16x8*)&AH_s[m * 392 + half * 192 + qd * 8 + u * 32];
                al[u] = *(const bf16x8*)&AL_s[m * 392 + half * 192 + qd * 8 + u * 32];
            }
            #pragma unroll
            for (int jj = 0; jj < 3; jj++) {
                int ct = jj * 8 + wv;
                #pragma unroll
                for (int u = 0; u < 6; u++) {
                    int kt = half * 6 + u;
                    size_t bo = ((size_t)(ct * 12 + kt) * 64 + lane) * 8;
                    bf16x8 bh = *(const bf16x8*)(B2_hi + bo);
                    bf16x8 bl = *(const bf16x8*)(B2_lo + bo);
                    dacc[jj] = __builtin_amdgcn_mfma_f32_16x16x32_bf16(al[u], bh, dacc[jj], 0, 0, 0);
                    dacc[jj] = __builtin_amdgcn_mfma_f32_16x16x32_bf16(ah[u], bl, dacc[jj], 0, 0, 0);
                    dacc[jj] = __builtin_amdgcn_mfma_f32_16x16x32_bf16(ah[u], bh, dacc[jj], 0, 0, 0);
                }
            }
        }
        const int c = wv * 16 + m;
        float bq = b_mix2[c], bs = b_mix2[128 + c], bu = b_mix2[256 + c];
        #pragma unroll
        for (int r = 0; r < 4; r++) {
            int node = qd * 4 + r;
            float dq   = dacc[0][r] + bq;
            float dms  = dacc[1][r] + bs;
            float dqmu = dacc[2][r] + bu;
            q_out[(size_t)(n0 + node) * H + c] =
                qn_s[node][c] + dq + dqmu * inner_s[node][c];
            #pragma unroll
            for (int d = 0; d < 3; d++) {
                size_t gi = ((size_t)(n0 + node) * 3 + d) * H + c;
                float mun = mu[gi] + acc_mu[(size_t)(n0 + node) * H3 + d * H + c];
                mu_out[gi] = mun + b2f(muw_s[node * 3 + d][c]) * dms;
            }
        }
    }
}

extern "C" void kernel_launch(void* const* d_in, const int* in_sizes, int n_in,
                              void* d_out, int out_size, void* d_ws, size_t ws_size,
                              hipStream_t stream) {
    const float* q        = (const float*)d_in[0];
    const float* mu       = (const float*)d_in[1];
    const int*   eidx     = (const int*)d_in[2];
    const float* rbf      = (const float*)d_in[3];
    const float* unitv    = (const float*)d_in[4];
    const float* cutoff   = (const float*)d_in[5];
    const float* W_inter1 = (const float*)d_in[6];
    const float* b_inter1 = (const float*)d_in[7];
    const float* W_inter2 = (const float*)d_in[8];
    const float* b_inter2 = (const float*)d_in[9];
    const float* W_filt1  = (const float*)d_in[10];
    const float* b_filt1  = (const float*)d_in[11];
    const float* W_filt2  = (const float*)d_in[12];
    const float* b_filt2  = (const float*)d_in[13];
    const float* W_vec    = (const float*)d_in[14];
    const float* W_mix1   = (const float*)d_in[15];
    const float* b_mix1   = (const float*)d_in[16];
    const float* W_mix2   = (const float*)d_in[17];
    const float* b_mix2   = (const float*)d_in[18];

    // workspace layout
    char* p = (char*)d_ws;
    float* acc_q       = (float*)p;            p += (size_t)NN * H * 4;
    float* acc_mu      = (float*)p;            p += (size_t)NN * H3 * 4;
    float* sorted_unit = (float*)p;            p += (size_t)NE * 3 * 4;
    int*   counts      = (int*)p;              p += (size_t)NN * 4;
    int*   off         = (int*)p;              p += (size_t)(NN + 1) * 4;
    p = (char*)(((size_t)p + 255) & ~(size_t)255);
    int*   cursor      = (int*)p;              p += (size_t)NN * 4;
    p = (char*)(((size_t)p + 255) & ~(size_t)255);
    int*   sorted_eid  = (int*)p;              p += (size_t)NE * 4;
    int*   sorted_src  = (int*)p;              p += (size_t)NE * 4;
    p = (char*)(((size_t)p + 255) & ~(size_t)255);
    unsigned short* Bp    = (unsigned short*)p; p += (size_t)H * H3 * 2;
    unsigned short* Bp1   = (unsigned short*)p; p += (size_t)H * H3 * 2;
    unsigned short* Bp2   = (unsigned short*)p; p += (size_t)H3 * H3 * 2;
    unsigned short* Bf1p  = (unsigned short*)p; p += (size_t)8 * 64 * 8 * 2;
    unsigned short* Bv_hi = (unsigned short*)p; p += (size_t)H * H2 * 2;
    unsigned short* Bv_lo = (unsigned short*)p; p += (size_t)H * H2 * 2;
    unsigned short* B1_hi = (unsigned short*)p; p += (size_t)H2 * H3 * 2;
    unsigned short* B1_lo = (unsigned short*)p; p += (size_t)H2 * H3 * 2;
    unsigned short* B2_hi = (unsigned short*)p; p += (size_t)H3 * H3 * 2;
    unsigned short* B2_lo = (unsigned short*)p; p += (size_t)H3 * H3 * 2;
    p = (char*)(((size_t)p + 255) & ~(size_t)255);
    unsigned short* x_b  = (unsigned short*)p;  p += (size_t)NN * H3 * 2;
    unsigned short* mu_b = (unsigned short*)p;  p += (size_t)NN * H3 * 2;
    p = (char*)(((size_t)p + 255) & ~(size_t)255);
    unsigned short* filt = (unsigned short*)p;  p += (size_t)NE * H3 * 2;

    float* q_out  = (float*)d_out;
    float* mu_out = q_out + (size_t)NN * H;

    hipMemsetAsync(counts, 0, (size_t)NN * 4, stream);

    hist_kernel    <<<NE / 256, 256, 0, stream>>>(eidx, counts);
    pack_all_kernel<<<1032, 64, 0, stream>>>(W_filt2, W_inter1, W_inter2, W_filt1,
                                             W_vec, W_mix1, W_mix2,
                                             Bp, Bp1, Bp2, Bf1p,
                                             Bv_hi, Bv_lo, B1_hi, B1_lo, B2_hi, B2_lo);
    scan_kernel    <<<1, 1024, 0, stream>>>(counts, off, cursor);
    mega_kernel    <<<NX_BLOCKS + PL_BLOCKS + MB_BLOCKS + FL_BLOCKS, 256, 0, stream>>>(
                       q, Bp1, b_inter1, Bp2, b_inter2, x_b,
                       eidx, unitv, cursor, sorted_eid, sorted_src, sorted_unit,
                       mu, mu_b,
                       rbf, cutoff, Bf1p, b_filt1, Bp, b_filt2, filt);
    gather_kernel  <<<NN, 256, 0, stream>>>(off, sorted_eid, sorted_src, sorted_unit,
                                            filt, x_b, mu_b, acc_q, acc_mu);
    mix_kernel     <<<NN / 16, 512, 0, stream>>>(q, mu, acc_q, acc_mu,
                                                 Bv_hi, Bv_lo, B1_hi, B1_lo, B2_hi, B2_lo,
                                                 b_mix1, b_mix2, q_out, mu_out);
}